// Round 1
// baseline (1586.661 us; speedup 1.0000x reference)
//
#include <hip/hip_runtime.h>
#include <hip/hip_bf16.h>

#define DD 128
#define EPSN 1e-12f

// ---------------------------------------------------------------------------
// T = X^T X  (D x D), atomic-accumulated over N-chunks.  grid(2,2,64) x 256
// ---------------------------------------------------------------------------
__global__ __launch_bounds__(256) void k_ata(const float* __restrict__ X,
                                             float* __restrict__ T,
                                             int chunkRows) {
  __shared__ float si[128][64];  // 32KB
  __shared__ float sj[128][64];  // 32KB
  const int bi = blockIdx.x, bj = blockIdx.y;
  const int n0 = blockIdx.z * chunkRows;  // chunkRows == 128
  const int t = threadIdx.x;
  for (int idx = t; idx < 128 * 16; idx += 256) {
    int r = idx >> 4, c4 = idx & 15;
    float4 a = *((const float4*)(X + (size_t)(n0 + r) * DD + bi * 64) + c4);
    float4 b = *((const float4*)(X + (size_t)(n0 + r) * DD + bj * 64) + c4);
    *(float4*)&si[r][c4 * 4] = a;
    *(float4*)&sj[r][c4 * 4] = b;
  }
  __syncthreads();
  const int tx = t & 15, ty = t >> 4;
  float acc[4][4] = {};
  for (int n = 0; n < 128; ++n) {
    float4 av = *(const float4*)&si[n][ty * 4];
    float4 bv = *(const float4*)&sj[n][tx * 4];
    float a[4] = {av.x, av.y, av.z, av.w};
    float b[4] = {bv.x, bv.y, bv.z, bv.w};
#pragma unroll
    for (int i = 0; i < 4; ++i)
#pragma unroll
      for (int j = 0; j < 4; ++j) acc[i][j] += a[i] * b[j];
  }
#pragma unroll
  for (int i = 0; i < 4; ++i)
#pragma unroll
    for (int j = 0; j < 4; ++j)
      atomicAdd(&T[(size_t)(bi * 64 + ty * 4 + i) * DD + bj * 64 + tx * 4 + j],
                acc[i][j]);
}

// ---------------------------------------------------------------------------
// out = l1norm_rows(X @ T)   (T is DxD, symmetric).  grid(N/32) x 512
// One wave per row -> row reduction entirely via shuffles.
// ---------------------------------------------------------------------------
__global__ __launch_bounds__(512) void k_two_hop(const float* __restrict__ X,
                                                 const float* __restrict__ T,
                                                 float* __restrict__ out) {
  __shared__ float Ts[128][128];  // 64KB exactly
  const int t = threadIdx.x;
  for (int idx = t; idx < 128 * 32; idx += 512) {
    int r = idx >> 5, c4 = idx & 31;
    *(float4*)&Ts[r][c4 * 4] = *((const float4*)(T + (size_t)r * DD) + c4);
  }
  __syncthreads();
  const int w = t >> 6, lane = t & 63;
  const int row0 = blockIdx.x * 32;
  for (int p = 0; p < 4; ++p) {
    const int r = row0 + p * 8 + w;
    const float* xr = X + (size_t)r * DD;
    float a0 = 0.f, a1 = 0.f;
    for (int k = 0; k < 128; k += 4) {
      float4 xv = *(const float4*)(xr + k);
      float xa[4] = {xv.x, xv.y, xv.z, xv.w};
#pragma unroll
      for (int q = 0; q < 4; ++q) {
        float2 tv = *(const float2*)&Ts[k + q][lane * 2];
        a0 += xa[q] * tv.x;
        a1 += xa[q] * tv.y;
      }
    }
    float ab = fabsf(a0) + fabsf(a1);
#pragma unroll
    for (int off = 1; off < 64; off <<= 1) ab += __shfl_xor(ab, off);
    const float inv = 1.f / fmaxf(ab, EPSN);
    float2 o;
    o.x = a0 * inv;
    o.y = a1 * inv;
    *(float2*)(out + (size_t)r * DD + lane * 2) = o;
  }
}

// ---------------------------------------------------------------------------
// Fused attention:  G = X Y^T (32 x N tile-strip), zero diag,
//   rabs[i]  += sum_j |G_ij|
//   Hacc[i,:] += sum_j G_ij * Y[j,:]
// grid(N/32, 2) x 256, j-split over blockIdx.y, atomic merge.
// Y staged transposed in LDS with float4-chunk XOR swizzle.
// ---------------------------------------------------------------------------
__global__ __launch_bounds__(256) void k_attn(const float* __restrict__ X,
                                              const float* __restrict__ Y,
                                              float* __restrict__ Hacc,
                                              float* __restrict__ rabs, int N) {
  __shared__ float xs[32][128];  // 16KB
  __shared__ float yt[128][64];  // 32KB: yt[k][swz(j)] = Y[j0+j][k]
  __shared__ float gt[32][64];   // 8KB
  const int t = threadIdx.x;
  const int i0 = blockIdx.x * 32;
  const int jbase = blockIdx.y * (N >> 1);
  for (int idx = t; idx < 32 * 32; idx += 256) {
    int r = idx >> 5, c4 = idx & 31;
    *(float4*)&xs[r][c4 * 4] = *((const float4*)(X + (size_t)(i0 + r) * DD) + c4);
  }
  const int tx = t & 15, ty = t >> 4;  // G map: cols 4tx.., rows ty, ty+16
  const int hx = t & 31, hy = t >> 5;  // H map: cols 4hx.., rows hy+8m
  float hacc[4][4] = {};
  float rloc[2] = {0.f, 0.f};
  const int jiters = (N >> 1) / 64;
  for (int jt = 0; jt < jiters; ++jt) {
    const int j0 = jbase + jt * 64;
    __syncthreads();  // previous iter's readers of yt/gt are done
    // stage yt[k][j] = Y[j0+j][k], chunk-swizzled: col = ((j>>2)^(k>>2 &15))*4 + (j&3)
    for (int idx = t; idx < 64 * 32; idx += 256) {
      int j = idx >> 5, dk = idx & 31;
      float4 v = *((const float4*)(Y + (size_t)(j0 + j) * DD) + dk);
      float va[4] = {v.x, v.y, v.z, v.w};
      int col = (((j >> 2) ^ (dk & 15)) << 2) + (j & 3);
#pragma unroll
      for (int q = 0; q < 4; ++q) yt[4 * dk + q][col] = va[q];
    }
    __syncthreads();
    // ---- G phase: g[m][c] = sum_k X[i0+r_m][k] * Y[j0+4tx+c][k]
    float g[2][4] = {};
    for (int k = 0; k < 128; k += 4) {
      float4 a0v = *(const float4*)&xs[ty][k];
      float4 a1v = *(const float4*)&xs[ty + 16][k];
      float a0[4] = {a0v.x, a0v.y, a0v.z, a0v.w};
      float a1[4] = {a1v.x, a1v.y, a1v.z, a1v.w};
      const int cs = ((tx ^ ((k >> 2) & 15)) << 2);
#pragma unroll
      for (int kk = 0; kk < 4; ++kk) {
        float4 bv = *(const float4*)&yt[k + kk][cs];
        float b[4] = {bv.x, bv.y, bv.z, bv.w};
#pragma unroll
        for (int c = 0; c < 4; ++c) {
          g[0][c] += a0[kk] * b[c];
          g[1][c] += a1[kk] * b[c];
        }
      }
    }
    // ---- diag zero + rowabs + stash G tile
#pragma unroll
    for (int m = 0; m < 2; ++m) {
      const int ig = i0 + ty + m * 16;
#pragma unroll
      for (int c = 0; c < 4; ++c) {
        if (ig == j0 + tx * 4 + c) g[m][c] = 0.f;
        rloc[m] += fabsf(g[m][c]);
      }
      *(float4*)&gt[ty + m * 16][tx * 4] =
          make_float4(g[m][0], g[m][1], g[m][2], g[m][3]);
    }
    __syncthreads();
    // ---- H phase: hacc[m][q] += sum_j gt[r_m][j] * Y[j0+j][4hx+q]
    for (int jj = 0; jj < 64; jj += 4) {
      float4 gm[4];
#pragma unroll
      for (int m = 0; m < 4; ++m) gm[m] = *(const float4*)&gt[hy + 8 * m][jj];
      const int csb = (((jj >> 2) ^ (hx & 15)) << 2);
#pragma unroll
      for (int q = 0; q < 4; ++q) {
        float4 yv = *(const float4*)&yt[4 * hx + q][csb];
        float yb[4] = {yv.x, yv.y, yv.z, yv.w};
#pragma unroll
        for (int m = 0; m < 4; ++m) {
          float ga[4] = {gm[m].x, gm[m].y, gm[m].z, gm[m].w};
#pragma unroll
          for (int wq = 0; wq < 4; ++wq) hacc[m][q] += ga[wq] * yb[wq];
        }
      }
    }
  }
  // rowabs: reduce across the 16 tx lanes sharing each row (contiguous lanes)
#pragma unroll
  for (int off = 1; off < 16; off <<= 1) {
    rloc[0] += __shfl_xor(rloc[0], off);
    rloc[1] += __shfl_xor(rloc[1], off);
  }
  if (tx == 0) {
    atomicAdd(&rabs[i0 + ty], rloc[0]);
    atomicAdd(&rabs[i0 + ty + 16], rloc[1]);
  }
#pragma unroll
  for (int m = 0; m < 4; ++m)
#pragma unroll
    for (int q = 0; q < 4; ++q)
      atomicAdd(&Hacc[(size_t)(i0 + hy + 8 * m) * DD + 4 * hx + q], hacc[m][q]);
}

// ---------------------------------------------------------------------------
// out = X @ W^T + b, with optional per-row scale 1/(max(rabs,eps)*N) on X.
// W staged in LDS with rotation swizzle (k+c)&127.  grid(N/32) x 512
// ---------------------------------------------------------------------------
__global__ __launch_bounds__(512) void k_linear(const float* __restrict__ X,
                                                const float* __restrict__ rabs,
                                                const float* __restrict__ W,
                                                const float* __restrict__ b,
                                                float* __restrict__ out, int N) {
  __shared__ float Ws[128][128];  // 64KB exactly
  const int t = threadIdx.x;
  for (int idx = t; idx < 128 * 32; idx += 512) {
    int c = idx >> 5, k4 = idx & 31;
    float4 v = *((const float4*)(W + (size_t)c * DD) + k4);
    float va[4] = {v.x, v.y, v.z, v.w};
#pragma unroll
    for (int q = 0; q < 4; ++q) Ws[c][(4 * k4 + q + c) & 127] = va[q];
  }
  __syncthreads();
  const int c = t & 127, rr = t >> 7;
  const int row0 = blockIdx.x * 32;
  const float bc = b[c];
  const float invN = 1.f / (float)N;
  for (int p = 0; p < 8; ++p) {
    const int r = row0 + p * 4 + rr;
    const float* xr = X + (size_t)r * DD;
    float dot = 0.f;
    for (int k = 0; k < 128; k += 4) {
      float4 xv = *(const float4*)(xr + k);
      float xa[4] = {xv.x, xv.y, xv.z, xv.w};
#pragma unroll
      for (int q = 0; q < 4; ++q) dot += xa[q] * Ws[c][(k + q + c) & 127];
    }
    float sc = 1.f;
    if (rabs) sc = invN / fmaxf(rabs[r], EPSN);
    out[(size_t)r * DD + c] = bc + sc * dot;
  }
}

// ---------------------------------------------------------------------------
// g = sigmoid(m@W1^T + b1 + s@W2^T + b2); out = base + g*m + (1-g)*s
// Two weight-staging phases share one 64KB LDS buffer. grid(N/32) x 512
// ---------------------------------------------------------------------------
__global__ __launch_bounds__(512) void k_gate(const float* __restrict__ m,
                                              const float* __restrict__ s,
                                              const float* __restrict__ W1,
                                              const float* __restrict__ b1,
                                              const float* __restrict__ W2,
                                              const float* __restrict__ b2,
                                              const float* __restrict__ base,
                                              float* __restrict__ out) {
  __shared__ float Ws[128][128];
  const int t = threadIdx.x;
  const int c = t & 127, rr = t >> 7;
  const int row0 = blockIdx.x * 32;
  float acc[8];
#pragma unroll
  for (int p = 0; p < 8; ++p) acc[p] = 0.f;

  for (int ph = 0; ph < 2; ++ph) {
    const float* W = ph ? W2 : W1;
    const float* X = ph ? s : m;
    for (int idx = t; idx < 128 * 32; idx += 512) {
      int cc = idx >> 5, k4 = idx & 31;
      float4 v = *((const float4*)(W + (size_t)cc * DD) + k4);
      float va[4] = {v.x, v.y, v.z, v.w};
#pragma unroll
      for (int q = 0; q < 4; ++q) Ws[cc][(4 * k4 + q + cc) & 127] = va[q];
    }
    __syncthreads();
    for (int p = 0; p < 8; ++p) {
      const float* xr = X + (size_t)(row0 + p * 4 + rr) * DD;
      float dot = 0.f;
      for (int k = 0; k < 128; k += 4) {
        float4 xv = *(const float4*)(xr + k);
        float xa[4] = {xv.x, xv.y, xv.z, xv.w};
#pragma unroll
        for (int q = 0; q < 4; ++q) dot += xa[q] * Ws[c][(k + q + c) & 127];
      }
      acc[p] += dot;
    }
    __syncthreads();  // before (possible) restage / exit
  }
  const float bb = b1[c] + b2[c];
  for (int p = 0; p < 8; ++p) {
    const size_t off = (size_t)(row0 + p * 4 + rr) * DD + c;
    const float g = 1.f / (1.f + __expf(-(acc[p] + bb)));
    out[off] = base[off] + g * m[off] + (1.f - g) * s[off];
  }
}

// ---------------------------------------------------------------------------
extern "C" void kernel_launch(void* const* d_in, const int* in_sizes, int n_in,
                              void* d_out, int out_size, void* d_ws,
                              size_t ws_size, hipStream_t stream) {
  const float* f1 = (const float*)d_in[0];
  const float* f2 = (const float*)d_in[1];
  const float* Wd1 = (const float*)d_in[2];
  const float* bd1 = (const float*)d_in[3];
  const float* Wd2 = (const float*)d_in[4];
  const float* bd2 = (const float*)d_in[5];
  const float* Ws1 = (const float*)d_in[6];
  const float* bs1 = (const float*)d_in[7];
  const float* Ws2 = (const float*)d_in[8];
  const float* bs2 = (const float*)d_in[9];
  const float* g1W1 = (const float*)d_in[10];
  const float* g1b1 = (const float*)d_in[11];
  const float* g1W2 = (const float*)d_in[12];
  const float* g1b2 = (const float*)d_in[13];
  const float* g2W1 = (const float*)d_in[14];
  const float* g2b1 = (const float*)d_in[15];
  const float* g2W2 = (const float*)d_in[16];
  const float* g2b2 = (const float*)d_in[17];

  const int N = in_sizes[0] / DD;  // 8192
  const size_t ND = (size_t)N * DD;

  float* ws = (float*)d_ws;
  float* T1 = ws;                  // D*D
  float* T2 = T1 + DD * DD;        // D*D
  float* HA = T2 + DD * DD;        // N*D   (H accumulator / pre-scaled A)
  float* rb = HA + ND;             // N     (row abs sums)
  float* mm = rb + N;              // N*D
  float* ss = mm + ND;             // N*D
  float* f1n = ss + ND;            // N*D
  float* base2 = f1n + ND;         // N*D
  float* out0 = (float*)d_out;     // user_d1
  float* out1 = out0 + ND;         // user_d2

  // --- two-hop terms via associativity: l1norm(X (X^T X)) ---
  hipMemsetAsync(T1, 0, sizeof(float) * 2 * DD * DD, stream);
  k_ata<<<dim3(2, 2, 64), 256, 0, stream>>>(f1, T1, N / 64);
  k_ata<<<dim3(2, 2, 64), 256, 0, stream>>>(f2, T2, N / 64);
  k_two_hop<<<N / 32, 512, 0, stream>>>(f1, T1, out0);   // user_d1
  k_two_hop<<<N / 32, 512, 0, stream>>>(f2, T2, base2);  // l1norm(f2 f2^T f2)

  // --- message block 1: d2 -> d1 ---
  hipMemsetAsync(HA, 0, sizeof(float) * (ND + N), stream);
  k_attn<<<dim3(N / 32, 2), 256, 0, stream>>>(f1, f2, HA, rb, N);
  k_linear<<<N / 32, 512, 0, stream>>>(HA, rb, Wd1, bd1, mm, N);       // msg_d2_d1
  k_linear<<<N / 32, 512, 0, stream>>>(f2, nullptr, Ws1, bs1, ss, N);  // msg_self
  k_gate<<<N / 32, 512, 0, stream>>>(mm, ss, g1W1, g1b1, g1W2, g1b2, out0,
                                     f1n);  // f1_new = user_d1 + msg_sum

  // --- message block 2: d1 -> d2 ---
  hipMemsetAsync(HA, 0, sizeof(float) * (ND + N), stream);
  k_attn<<<dim3(N / 32, 2), 256, 0, stream>>>(f2, f1n, HA, rb, N);
  k_linear<<<N / 32, 512, 0, stream>>>(HA, rb, Wd2, bd2, mm, N);        // msg_d1_d2
  k_linear<<<N / 32, 512, 0, stream>>>(f1n, nullptr, Ws2, bs2, ss, N);  // msg_self2
  k_gate<<<N / 32, 512, 0, stream>>>(mm, ss, g2W1, g2b1, g2W2, g2b2, base2,
                                     out1);  // user_d2
}

// Round 2
// 527.944 us; speedup vs baseline: 3.0054x; 3.0054x over previous
//
#include <hip/hip_runtime.h>
#include <hip/hip_bf16.h>

#define DD 128
#define EPSN 1e-12f

typedef __attribute__((ext_vector_type(8))) short bf16x8;
typedef __attribute__((ext_vector_type(16))) float f32x16;

__device__ __forceinline__ unsigned short f2b(float f) {
  unsigned int u = __builtin_bit_cast(unsigned int, f);
  return (unsigned short)((u + 0x7fffu + ((u >> 16) & 1u)) >> 16);
}

// ---------------------------------------------------------------------------
// fp32 -> bf16 copy.  n4 = n/4.
// ---------------------------------------------------------------------------
__global__ __launch_bounds__(256) void k_cvt(const float* __restrict__ x,
                                             unsigned short* __restrict__ y,
                                             int n4) {
  int i = blockIdx.x * 256 + threadIdx.x;
  if (i < n4) {
    float4 v = ((const float4*)x)[i];
    ushort4 o;
    o.x = f2b(v.x); o.y = f2b(v.y); o.z = f2b(v.z); o.w = f2b(v.w);
    ((ushort4*)y)[i] = o;
  }
}

// ---------------------------------------------------------------------------
// T = X^T X  (D x D), atomic-accumulated over N-chunks.  grid(2,2,64) x 256
// ---------------------------------------------------------------------------
__global__ __launch_bounds__(256) void k_ata(const float* __restrict__ X,
                                             float* __restrict__ T,
                                             int chunkRows) {
  __shared__ float si[128][64];
  __shared__ float sj[128][64];
  const int bi = blockIdx.x, bj = blockIdx.y;
  const int n0 = blockIdx.z * chunkRows;
  const int t = threadIdx.x;
  for (int idx = t; idx < 128 * 16; idx += 256) {
    int r = idx >> 4, c4 = idx & 15;
    float4 a = *((const float4*)(X + (size_t)(n0 + r) * DD + bi * 64) + c4);
    float4 b = *((const float4*)(X + (size_t)(n0 + r) * DD + bj * 64) + c4);
    *(float4*)&si[r][c4 * 4] = a;
    *(float4*)&sj[r][c4 * 4] = b;
  }
  __syncthreads();
  const int tx = t & 15, ty = t >> 4;
  float acc[4][4] = {};
  for (int n = 0; n < 128; ++n) {
    float4 av = *(const float4*)&si[n][ty * 4];
    float4 bv = *(const float4*)&sj[n][tx * 4];
    float a[4] = {av.x, av.y, av.z, av.w};
    float b[4] = {bv.x, bv.y, bv.z, bv.w};
#pragma unroll
    for (int i = 0; i < 4; ++i)
#pragma unroll
      for (int j = 0; j < 4; ++j) acc[i][j] += a[i] * b[j];
  }
#pragma unroll
  for (int i = 0; i < 4; ++i)
#pragma unroll
    for (int j = 0; j < 4; ++j)
      atomicAdd(&T[(size_t)(bi * 64 + ty * 4 + i) * DD + bj * 64 + tx * 4 + j],
                acc[i][j]);
}

// ---------------------------------------------------------------------------
// out = l1norm_rows(X @ T).  grid(N/32) x 512
// ---------------------------------------------------------------------------
__global__ __launch_bounds__(512) void k_two_hop(const float* __restrict__ X,
                                                 const float* __restrict__ T,
                                                 float* __restrict__ out) {
  __shared__ float Ts[128][128];
  const int t = threadIdx.x;
  for (int idx = t; idx < 128 * 32; idx += 512) {
    int r = idx >> 5, c4 = idx & 31;
    *(float4*)&Ts[r][c4 * 4] = *((const float4*)(T + (size_t)r * DD) + c4);
  }
  __syncthreads();
  const int w = t >> 6, lane = t & 63;
  const int row0 = blockIdx.x * 32;
  for (int p = 0; p < 4; ++p) {
    const int r = row0 + p * 8 + w;
    const float* xr = X + (size_t)r * DD;
    float a0 = 0.f, a1 = 0.f;
    for (int k = 0; k < 128; k += 4) {
      float4 xv = *(const float4*)(xr + k);
      float xa[4] = {xv.x, xv.y, xv.z, xv.w};
#pragma unroll
      for (int q = 0; q < 4; ++q) {
        float2 tv = *(const float2*)&Ts[k + q][lane * 2];
        a0 += xa[q] * tv.x;
        a1 += xa[q] * tv.y;
      }
    }
    float ab = fabsf(a0) + fabsf(a1);
#pragma unroll
    for (int off = 1; off < 64; off <<= 1) ab += __shfl_xor(ab, off);
    const float inv = 1.f / fmaxf(ab, EPSN);
    float2 o;
    o.x = a0 * inv;
    o.y = a1 * inv;
    *(float2*)(out + (size_t)r * DD + lane * 2) = o;
  }
}

// ---------------------------------------------------------------------------
// MFMA fused attention.  X,Y bf16.  Per block: 64 i-rows, j-split over
// blockIdx.y.  Phase 1: S(64x64) = X Y^T (diag-zeroed, |S| row-sums).
// Phase 2: H(64x128) += S Y  accumulated in registers, atomic epilogue.
// All LDS tiles 16B-chunk XOR-swizzled for conflict-free ds_read_b128.
// grid(N/64, JSPLIT) x 256 (4 waves).
// ---------------------------------------------------------------------------
#define JSPLIT 4
__global__ __launch_bounds__(256, 2) void k_attn(
    const unsigned short* __restrict__ Xb, const unsigned short* __restrict__ Yb,
    float* __restrict__ HA, float* __restrict__ rabs, int N) {
  __shared__ unsigned short Xs[64][128];  // 16KB  chunk swz: c^(row&15)
  __shared__ unsigned short Ys[64][128];  // 16KB  chunk swz: c^(row&15)
  __shared__ unsigned short Yt[128][64];  // 16KB  d-major, swz: c^(d&7)
  __shared__ unsigned short Ss[64][64];   // 8KB   i-major, swz: c^(i&7)
  const int t = threadIdx.x;
  const int w = t >> 6, l = t & 63, lh = l >> 5, ln = l & 31;
  const int i0 = blockIdx.x * 64;
  const int jbase = blockIdx.y * (N / JSPLIT);
  const int jiters = (N / JSPLIT) / 64;

  // stage X tile once
  for (int it = t; it < 1024; it += 256) {
    int r = it >> 4, c = it & 15;
    *(bf16x8*)&Xs[r][(c ^ (r & 15)) << 3] =
        *(const bf16x8*)(Xb + (size_t)(i0 + r) * DD + (c << 3));
  }

  f32x16 acc2[2];
  float rloc[16];
#pragma unroll
  for (int r = 0; r < 16; ++r) {
    acc2[0][r] = 0.f;
    acc2[1][r] = 0.f;
    rloc[r] = 0.f;
  }

  const int ar = (w >> 1) * 32 + ln;  // X row (i-local), also Ss row in ph2
  const int br = (w & 1) * 32 + ln;   // Y row (j-local) for ph1 B
  const int R0 = i0 + (w >> 1) * 32;  // global row base of this wave's S tile

  for (int jt = 0; jt < jiters; ++jt) {
    const int j0 = jbase + jt * 64;
    __syncthreads();  // prev iter's readers of Ys/Yt/Ss done
    // ---- stage Y tile: Ys row-major + Yt d-major (packed u32 writes)
    for (int it = t; it < 512; it += 256) {
      int jp = it & 31, d8 = it >> 5;
      const unsigned short* ya = Yb + (size_t)(j0 + 2 * jp) * DD + (d8 << 3);
      bf16x8 a = *(const bf16x8*)ya;
      bf16x8 b = *(const bf16x8*)(ya + DD);
      int ja = 2 * jp, jb = ja + 1;
      *(bf16x8*)&Ys[ja][(d8 ^ (ja & 15)) << 3] = a;
      *(bf16x8*)&Ys[jb][(d8 ^ (jb & 15)) << 3] = b;
#pragma unroll
      for (int e = 0; e < 8; ++e) {
        int d = (d8 << 3) + e;
        unsigned int pv =
            (unsigned short)a[e] | ((unsigned int)(unsigned short)b[e] << 16);
        int cpr = (jp >> 2) ^ (d & 7);
        *(unsigned int*)&Yt[d][(cpr << 3) + ((jp & 3) << 1)] = pv;
      }
    }
    __syncthreads();
    // ---- phase 1: S tile = X Y^T
    f32x16 s;
#pragma unroll
    for (int r = 0; r < 16; ++r) s[r] = 0.f;
#pragma unroll
    for (int k0 = 0; k0 < 128; k0 += 16) {
      int ck = (k0 >> 3) + lh;
      bf16x8 av = *(const bf16x8*)&Xs[ar][((ck ^ (ar & 15)) << 3)];
      bf16x8 bv = *(const bf16x8*)&Ys[br][((ck ^ (br & 15)) << 3)];
      s = __builtin_amdgcn_mfma_f32_32x32x16_bf16(av, bv, s, 0, 0, 0);
    }
    // ---- diag zero (only when tile sits on the diagonal)
    const int C0 = j0 + (w & 1) * 32;
    if (R0 == C0) {
#pragma unroll
      for (int r = 0; r < 16; ++r) {
        int row = (r & 3) + 8 * (r >> 2) + 4 * lh;
        if (row == ln) s[r] = 0.f;
      }
    }
    // ---- rowabs accumulate + S -> bf16 LDS
#pragma unroll
    for (int r = 0; r < 16; ++r) {
      float v = s[r];
      rloc[r] += fabsf(v);
      int il = (w >> 1) * 32 + (r & 3) + 8 * (r >> 2) + 4 * lh;  // i-local
      int jl = (w & 1) * 32 + ln;                                // j-local
      int cc = (jl >> 3) ^ (il & 7);
      Ss[il][(cc << 3) + (jl & 7)] = f2b(v);
    }
    __syncthreads();
    // ---- phase 2: H += S Y
#pragma unroll
    for (int k0 = 0; k0 < 64; k0 += 16) {
      int ck = (k0 >> 3) + lh;
      bf16x8 av = *(const bf16x8*)&Ss[ar][((ck ^ (ar & 7)) << 3)];
#pragma unroll
      for (int cb = 0; cb < 2; ++cb) {
        int nr = ((w & 1) * 2 + cb) * 32 + ln;  // d index (Yt row)
        bf16x8 bv = *(const bf16x8*)&Yt[nr][((ck ^ (nr & 7)) << 3)];
        acc2[cb] = __builtin_amdgcn_mfma_f32_32x32x16_bf16(av, bv, acc2[cb], 0, 0, 0);
      }
    }
  }
  // ---- epilogue: rowabs reduce across the 32 j-lanes, then atomics
#pragma unroll
  for (int r = 0; r < 16; ++r) {
    float v = rloc[r];
#pragma unroll
    for (int off = 1; off < 32; off <<= 1) v += __shfl_xor(v, off);
    rloc[r] = v;
  }
  if (ln == 0) {
#pragma unroll
    for (int r = 0; r < 16; ++r) {
      int row = i0 + (w >> 1) * 32 + (r & 3) + 8 * (r >> 2) + 4 * lh;
      atomicAdd(&rabs[row], rloc[r]);
    }
  }
#pragma unroll
  for (int cb = 0; cb < 2; ++cb)
#pragma unroll
    for (int r = 0; r < 16; ++r) {
      int row = i0 + (w >> 1) * 32 + (r & 3) + 8 * (r >> 2) + 4 * lh;
      int d = ((w & 1) * 2 + cb) * 32 + ln;
      atomicAdd(&HA[(size_t)row * DD + d], acc2[cb][r]);
    }
}

// ---------------------------------------------------------------------------
// out = X @ W^T + b, optional per-row scale 1/(max(rabs,eps)*N) on X.
// ---------------------------------------------------------------------------
__global__ __launch_bounds__(512) void k_linear(const float* __restrict__ X,
                                                const float* __restrict__ rabs,
                                                const float* __restrict__ W,
                                                const float* __restrict__ b,
                                                float* __restrict__ out, int N) {
  __shared__ float Ws[128][128];
  const int t = threadIdx.x;
  for (int idx = t; idx < 128 * 32; idx += 512) {
    int c = idx >> 5, k4 = idx & 31;
    float4 v = *((const float4*)(W + (size_t)c * DD) + k4);
    float va[4] = {v.x, v.y, v.z, v.w};
#pragma unroll
    for (int q = 0; q < 4; ++q) Ws[c][(4 * k4 + q + c) & 127] = va[q];
  }
  __syncthreads();
  const int c = t & 127, rr = t >> 7;
  const int row0 = blockIdx.x * 32;
  const float bc = b[c];
  const float invN = 1.f / (float)N;
  for (int p = 0; p < 8; ++p) {
    const int r = row0 + p * 4 + rr;
    const float* xr = X + (size_t)r * DD;
    float dot = 0.f;
    for (int k = 0; k < 128; k += 4) {
      float4 xv = *(const float4*)(xr + k);
      float xa[4] = {xv.x, xv.y, xv.z, xv.w};
#pragma unroll
      for (int q = 0; q < 4; ++q) dot += xa[q] * Ws[c][(k + q + c) & 127];
    }
    float sc = 1.f;
    if (rabs) sc = invN / fmaxf(rabs[r], EPSN);
    out[(size_t)r * DD + c] = bc + sc * dot;
  }
}

// ---------------------------------------------------------------------------
// g = sigmoid(m@W1^T + b1 + s@W2^T + b2); out = base + g*m + (1-g)*s
// Optionally also writes bf16 copy of out.
// ---------------------------------------------------------------------------
__global__ __launch_bounds__(512) void k_gate(const float* __restrict__ m,
                                              const float* __restrict__ s,
                                              const float* __restrict__ W1,
                                              const float* __restrict__ b1,
                                              const float* __restrict__ W2,
                                              const float* __restrict__ b2,
                                              const float* __restrict__ base,
                                              float* __restrict__ out,
                                              unsigned short* __restrict__ outb) {
  __shared__ float Ws[128][128];
  const int t = threadIdx.x;
  const int c = t & 127, rr = t >> 7;
  const int row0 = blockIdx.x * 32;
  float acc[8];
#pragma unroll
  for (int p = 0; p < 8; ++p) acc[p] = 0.f;

  for (int ph = 0; ph < 2; ++ph) {
    const float* W = ph ? W2 : W1;
    const float* X = ph ? s : m;
    for (int idx = t; idx < 128 * 32; idx += 512) {
      int cc = idx >> 5, k4 = idx & 31;
      float4 v = *((const float4*)(W + (size_t)cc * DD) + k4);
      float va[4] = {v.x, v.y, v.z, v.w};
#pragma unroll
      for (int q = 0; q < 4; ++q) Ws[cc][(4 * k4 + q + cc) & 127] = va[q];
    }
    __syncthreads();
    for (int p = 0; p < 8; ++p) {
      const float* xr = X + (size_t)(row0 + p * 4 + rr) * DD;
      float dot = 0.f;
      for (int k = 0; k < 128; k += 4) {
        float4 xv = *(const float4*)(xr + k);
        float xa[4] = {xv.x, xv.y, xv.z, xv.w};
#pragma unroll
        for (int q = 0; q < 4; ++q) dot += xa[q] * Ws[c][(k + q + c) & 127];
      }
      acc[p] += dot;
    }
    __syncthreads();
  }
  const float bb = b1[c] + b2[c];
  for (int p = 0; p < 8; ++p) {
    const size_t off = (size_t)(row0 + p * 4 + rr) * DD + c;
    const float g = 1.f / (1.f + __expf(-(acc[p] + bb)));
    const float val = base[off] + g * m[off] + (1.f - g) * s[off];
    out[off] = val;
    if (outb) outb[off] = f2b(val);
  }
}

// ---------------------------------------------------------------------------
extern "C" void kernel_launch(void* const* d_in, const int* in_sizes, int n_in,
                              void* d_out, int out_size, void* d_ws,
                              size_t ws_size, hipStream_t stream) {
  const float* f1 = (const float*)d_in[0];
  const float* f2 = (const float*)d_in[1];
  const float* Wd1 = (const float*)d_in[2];
  const float* bd1 = (const float*)d_in[3];
  const float* Wd2 = (const float*)d_in[4];
  const float* bd2 = (const float*)d_in[5];
  const float* Ws1 = (const float*)d_in[6];
  const float* bs1 = (const float*)d_in[7];
  const float* Ws2 = (const float*)d_in[8];
  const float* bs2 = (const float*)d_in[9];
  const float* g1W1 = (const float*)d_in[10];
  const float* g1b1 = (const float*)d_in[11];
  const float* g1W2 = (const float*)d_in[12];
  const float* g1b2 = (const float*)d_in[13];
  const float* g2W1 = (const float*)d_in[14];
  const float* g2b1 = (const float*)d_in[15];
  const float* g2W2 = (const float*)d_in[16];
  const float* g2b2 = (const float*)d_in[17];

  const int N = in_sizes[0] / DD;  // 8192
  const size_t ND = (size_t)N * DD;

  float* ws = (float*)d_ws;
  float* T1 = ws;                  // D*D
  float* T2 = T1 + DD * DD;        // D*D
  float* HA = T2 + DD * DD;        // N*D
  float* rb = HA + ND;             // N
  float* mm = rb + N;              // N*D
  float* ss = mm + ND;             // N*D
  float* f1n = ss + ND;            // N*D
  float* base2 = f1n + ND;         // N*D
  unsigned short* f1bb = (unsigned short*)(base2 + ND);  // N*D bf16
  unsigned short* f2bb = f1bb + ND;                      // N*D bf16
  unsigned short* f1nb = f2bb + ND;                      // N*D bf16
  float* out0 = (float*)d_out;
  float* out1 = out0 + ND;

  const int cvtGrid = (int)((ND / 4 + 255) / 256);
  k_cvt<<<cvtGrid, 256, 0, stream>>>(f1, f1bb, (int)(ND / 4));
  k_cvt<<<cvtGrid, 256, 0, stream>>>(f2, f2bb, (int)(ND / 4));

  // --- two-hop terms via associativity: l1norm(X (X^T X)) ---
  hipMemsetAsync(T1, 0, sizeof(float) * 2 * DD * DD, stream);
  k_ata<<<dim3(2, 2, 64), 256, 0, stream>>>(f1, T1, N / 64);
  k_ata<<<dim3(2, 2, 64), 256, 0, stream>>>(f2, T2, N / 64);
  k_two_hop<<<N / 32, 512, 0, stream>>>(f1, T1, out0);   // user_d1
  k_two_hop<<<N / 32, 512, 0, stream>>>(f2, T2, base2);  // l1norm(f2 f2^T f2)

  // --- message block 1: d2 -> d1 ---
  hipMemsetAsync(HA, 0, sizeof(float) * (ND + N), stream);
  k_attn<<<dim3(N / 64, JSPLIT), 256, 0, stream>>>(f1bb, f2bb, HA, rb, N);
  k_linear<<<N / 32, 512, 0, stream>>>(HA, rb, Wd1, bd1, mm, N);
  k_linear<<<N / 32, 512, 0, stream>>>(f2, nullptr, Ws1, bs1, ss, N);
  k_gate<<<N / 32, 512, 0, stream>>>(mm, ss, g1W1, g1b1, g1W2, g1b2, out0, f1n,
                                     f1nb);

  // --- message block 2: d1 -> d2 ---
  hipMemsetAsync(HA, 0, sizeof(float) * (ND + N), stream);
  k_attn<<<dim3(N / 64, JSPLIT), 256, 0, stream>>>(f2bb, f1nb, HA, rb, N);
  k_linear<<<N / 32, 512, 0, stream>>>(HA, rb, Wd2, bd2, mm, N);
  k_linear<<<N / 32, 512, 0, stream>>>(f1n, nullptr, Ws2, bs2, ss, N);
  k_gate<<<N / 32, 512, 0, stream>>>(mm, ss, g2W1, g2b1, g2W2, g2b2, base2,
                                     out1, nullptr);
}

// Round 3
// 276.239 us; speedup vs baseline: 5.7438x; 1.9112x over previous
//
#include <hip/hip_runtime.h>
#include <hip/hip_bf16.h>

#define DD 128
#define EPSN 1e-12f

typedef __attribute__((ext_vector_type(8))) short bf16x8;
typedef __attribute__((ext_vector_type(16))) float f32x16;

__device__ __forceinline__ unsigned short f2b(float f) {
  unsigned int u = __builtin_bit_cast(unsigned int, f);
  return (unsigned short)((u + 0x7fffu + ((u >> 16) & 1u)) >> 16);
}
__device__ __forceinline__ float b2f(unsigned short u) {
  unsigned int v = ((unsigned int)u) << 16;
  return __builtin_bit_cast(float, v);
}

// ---------------------------------------------------------------------------
// fp32 -> bf16 copy.  n4 = n/4.
// ---------------------------------------------------------------------------
__global__ __launch_bounds__(256) void k_cvt(const float* __restrict__ x,
                                             unsigned short* __restrict__ y,
                                             int n4) {
  int i = blockIdx.x * 256 + threadIdx.x;
  if (i < n4) {
    float4 v = ((const float4*)x)[i];
    ushort4 o;
    o.x = f2b(v.x); o.y = f2b(v.y); o.z = f2b(v.z); o.w = f2b(v.w);
    ((ushort4*)y)[i] = o;
  }
}

// ---------------------------------------------------------------------------
// T = X^T X  (D x D, symmetric), atomic-accumulated.  grid(2,2,64) x 256
// ---------------------------------------------------------------------------
__global__ __launch_bounds__(256) void k_ata(const float* __restrict__ X,
                                             float* __restrict__ T,
                                             int chunkRows) {
  __shared__ float si[128][64];
  __shared__ float sj[128][64];
  const int bi = blockIdx.x, bj = blockIdx.y;
  const int n0 = blockIdx.z * chunkRows;
  const int t = threadIdx.x;
  for (int idx = t; idx < 128 * 16; idx += 256) {
    int r = idx >> 4, c4 = idx & 15;
    float4 a = *((const float4*)(X + (size_t)(n0 + r) * DD + bi * 64) + c4);
    float4 b = *((const float4*)(X + (size_t)(n0 + r) * DD + bj * 64) + c4);
    *(float4*)&si[r][c4 * 4] = a;
    *(float4*)&sj[r][c4 * 4] = b;
  }
  __syncthreads();
  const int tx = t & 15, ty = t >> 4;
  float acc[4][4] = {};
  for (int n = 0; n < 128; ++n) {
    float4 av = *(const float4*)&si[n][ty * 4];
    float4 bv = *(const float4*)&sj[n][tx * 4];
    float a[4] = {av.x, av.y, av.z, av.w};
    float b[4] = {bv.x, bv.y, bv.z, bv.w};
#pragma unroll
    for (int i = 0; i < 4; ++i)
#pragma unroll
      for (int j = 0; j < 4; ++j) acc[i][j] += a[i] * b[j];
  }
#pragma unroll
  for (int i = 0; i < 4; ++i)
#pragma unroll
    for (int j = 0; j < 4; ++j)
      atomicAdd(&T[(size_t)(bi * 64 + ty * 4 + i) * DD + bj * 64 + tx * 4 + j],
                acc[i][j]);
}

// ---------------------------------------------------------------------------
// MFMA fused attention (unchanged from R1 — passes, 86us).
// ---------------------------------------------------------------------------
#define JSPLIT 4
__global__ __launch_bounds__(256, 2) void k_attn(
    const unsigned short* __restrict__ Xb, const unsigned short* __restrict__ Yb,
    float* __restrict__ HA, float* __restrict__ rabs, int N) {
  __shared__ unsigned short Xs[64][128];
  __shared__ unsigned short Ys[64][128];
  __shared__ unsigned short Yt[128][64];
  __shared__ unsigned short Ss[64][64];
  const int t = threadIdx.x;
  const int w = t >> 6, l = t & 63, lh = l >> 5, ln = l & 31;
  const int i0 = blockIdx.x * 64;
  const int jbase = blockIdx.y * (N / JSPLIT);
  const int jiters = (N / JSPLIT) / 64;

  for (int it = t; it < 1024; it += 256) {
    int r = it >> 4, c = it & 15;
    *(bf16x8*)&Xs[r][(c ^ (r & 15)) << 3] =
        *(const bf16x8*)(Xb + (size_t)(i0 + r) * DD + (c << 3));
  }

  f32x16 acc2[2];
  float rloc[16];
#pragma unroll
  for (int r = 0; r < 16; ++r) {
    acc2[0][r] = 0.f;
    acc2[1][r] = 0.f;
    rloc[r] = 0.f;
  }

  const int ar = (w >> 1) * 32 + ln;
  const int br = (w & 1) * 32 + ln;
  const int R0 = i0 + (w >> 1) * 32;

  for (int jt = 0; jt < jiters; ++jt) {
    const int j0 = jbase + jt * 64;
    __syncthreads();
    for (int it = t; it < 512; it += 256) {
      int jp = it & 31, d8 = it >> 5;
      const unsigned short* ya = Yb + (size_t)(j0 + 2 * jp) * DD + (d8 << 3);
      bf16x8 a = *(const bf16x8*)ya;
      bf16x8 b = *(const bf16x8*)(ya + DD);
      int ja = 2 * jp, jb = ja + 1;
      *(bf16x8*)&Ys[ja][(d8 ^ (ja & 15)) << 3] = a;
      *(bf16x8*)&Ys[jb][(d8 ^ (jb & 15)) << 3] = b;
#pragma unroll
      for (int e = 0; e < 8; ++e) {
        int d = (d8 << 3) + e;
        unsigned int pv =
            (unsigned short)a[e] | ((unsigned int)(unsigned short)b[e] << 16);
        int cpr = (jp >> 2) ^ (d & 7);
        *(unsigned int*)&Yt[d][(cpr << 3) + ((jp & 3) << 1)] = pv;
      }
    }
    __syncthreads();
    f32x16 s;
#pragma unroll
    for (int r = 0; r < 16; ++r) s[r] = 0.f;
#pragma unroll
    for (int k0 = 0; k0 < 128; k0 += 16) {
      int ck = (k0 >> 3) + lh;
      bf16x8 av = *(const bf16x8*)&Xs[ar][((ck ^ (ar & 15)) << 3)];
      bf16x8 bv = *(const bf16x8*)&Ys[br][((ck ^ (br & 15)) << 3)];
      s = __builtin_amdgcn_mfma_f32_32x32x16_bf16(av, bv, s, 0, 0, 0);
    }
    const int C0 = j0 + (w & 1) * 32;
    if (R0 == C0) {
#pragma unroll
      for (int r = 0; r < 16; ++r) {
        int rrow = (r & 3) + 8 * (r >> 2) + 4 * lh;
        if (rrow == ln) s[r] = 0.f;
      }
    }
#pragma unroll
    for (int r = 0; r < 16; ++r) {
      float v = s[r];
      rloc[r] += fabsf(v);
      int il = (w >> 1) * 32 + (r & 3) + 8 * (r >> 2) + 4 * lh;
      int jl = (w & 1) * 32 + ln;
      int cc = (jl >> 3) ^ (il & 7);
      Ss[il][(cc << 3) + (jl & 7)] = f2b(v);
    }
    __syncthreads();
#pragma unroll
    for (int k0 = 0; k0 < 64; k0 += 16) {
      int ck = (k0 >> 3) + lh;
      bf16x8 av = *(const bf16x8*)&Ss[ar][((ck ^ (ar & 7)) << 3)];
#pragma unroll
      for (int cb = 0; cb < 2; ++cb) {
        int nr = ((w & 1) * 2 + cb) * 32 + ln;
        bf16x8 bv = *(const bf16x8*)&Yt[nr][((ck ^ (nr & 7)) << 3)];
        acc2[cb] = __builtin_amdgcn_mfma_f32_32x32x16_bf16(av, bv, acc2[cb], 0, 0, 0);
      }
    }
  }
#pragma unroll
  for (int r = 0; r < 16; ++r) {
    float v = rloc[r];
#pragma unroll
    for (int off = 1; off < 32; off <<= 1) v += __shfl_xor(v, off);
    rloc[r] = v;
  }
  if (ln == 0) {
#pragma unroll
    for (int r = 0; r < 16; ++r) {
      int rrow = i0 + (w >> 1) * 32 + (r & 3) + 8 * (r >> 2) + 4 * lh;
      atomicAdd(&rabs[rrow], rloc[r]);
    }
  }
#pragma unroll
  for (int cb = 0; cb < 2; ++cb)
#pragma unroll
    for (int r = 0; r < 16; ++r) {
      int rrow = i0 + (w >> 1) * 32 + (r & 3) + 8 * (r >> 2) + 4 * lh;
      int d = ((w & 1) * 2 + cb) * 32 + ln;
      atomicAdd(&HA[(size_t)rrow * DD + d], acc2[cb][r]);
    }
}

// ---------------------------------------------------------------------------
// Fused post-attention chain, all in "T-layout" (acc lane = row i):
//   basen = l1norm(Xbase @ T)         (T symmetric -> A-op = T rows)
//   m     = (HA*scale) @ Wm^T + bm
//   s     = Xself @ Ws^T + bs
//   z     = m @ Wg1^T + s @ Wg2^T + (bg1+bg2);  g = sigmoid(z)
//   val   = basen + g*m + (1-g)*s
// Outputs (optional each): outNorm=basen (f32), outValF=val (f32),
// outValB=val (bf16).  grid(N/32) x 256 (4 waves = 4 c-quarters).
// ---------------------------------------------------------------------------
__device__ __forceinline__ void stageW(const unsigned short* __restrict__ g,
                                       unsigned short (*L)[128], int t) {
#pragma unroll
  for (int idx = t; idx < 2048; idx += 256) {
    int r = idx >> 4, ch = idx & 15;
    *(bf16x8*)&L[r][(ch ^ (r & 15)) << 3] = *(const bf16x8*)(g + r * 128 + ch * 8);
  }
}
__device__ __forceinline__ bf16x8 wfrag(const unsigned short (*L)[128], int row,
                                        int kc, int lh) {
  int ch = kc * 2 + lh;
  return *(const bf16x8*)&L[row][(ch ^ (row & 15)) << 3];
}

__global__ __launch_bounds__(256) void k_post(
    const float* __restrict__ HA, const float* __restrict__ rb,
    const unsigned short* __restrict__ fselfb,
    const unsigned short* __restrict__ fbaseb,
    const unsigned short* __restrict__ Tb,
    const unsigned short* __restrict__ Wmb, const float* __restrict__ bm,
    const unsigned short* __restrict__ Wsb, const float* __restrict__ bs,
    const unsigned short* __restrict__ Wg1b, const float* __restrict__ bg1,
    const unsigned short* __restrict__ Wg2b, const float* __restrict__ bg2,
    float* __restrict__ outNorm, float* __restrict__ outValF,
    unsigned short* __restrict__ outValB, int N) {
  __shared__ unsigned short WL[128][128];        // 32KB weight stage
  __shared__ __align__(16) char pool[32 * 132 * 4];  // Mb+Sb, later transpose
  __shared__ float blds[3][128];
  __shared__ float rowpart[4][32];
  unsigned short(*Mb)[128] = (unsigned short(*)[128])pool;
  unsigned short(*Sb)[128] = (unsigned short(*)[128])(pool + 8192);
  float(*tr)[132] = (float(*)[132])pool;

  const int t = threadIdx.x;
  const int w = t >> 6, l = t & 63, ln = l & 31, lh = l >> 5;
  const int i0 = blockIdx.x * 32;
  const int row = i0 + ln;
  const int cq = w;

  // per-lane row fragments (lane = row i; k = kc*16 + lh*8 + e)
  const float sc = (1.f / (float)N) / fmaxf(rb[row], EPSN);
  bf16x8 bfA[8], bfS[8], bfB[8];
#pragma unroll
  for (int kc = 0; kc < 8; ++kc) {
    const float* hp = HA + (size_t)row * DD + kc * 16 + lh * 8;
    float4 u = *(const float4*)hp;
    float4 v = *(const float4*)(hp + 4);
    bf16x8 a;
    a[0] = (short)f2b(u.x * sc); a[1] = (short)f2b(u.y * sc);
    a[2] = (short)f2b(u.z * sc); a[3] = (short)f2b(u.w * sc);
    a[4] = (short)f2b(v.x * sc); a[5] = (short)f2b(v.y * sc);
    a[6] = (short)f2b(v.z * sc); a[7] = (short)f2b(v.w * sc);
    bfA[kc] = a;
    bfS[kc] = *(const bf16x8*)(fselfb + (size_t)row * DD + kc * 16 + lh * 8);
    bfB[kc] = *(const bf16x8*)(fbaseb + (size_t)row * DD + kc * 16 + lh * 8);
  }
  if (t < 128) {
    blds[0][t] = bm[t];
    blds[1][t] = bs[t];
    blds[2][t] = bg1[t] + bg2[t];
  }
  stageW(Tb, WL, t);
  __syncthreads();

  // ---- baseT + l1norm
  f32x16 acc;
#pragma unroll
  for (int r = 0; r < 16; ++r) acc[r] = 0.f;
#pragma unroll
  for (int kc = 0; kc < 8; ++kc)
    acc = __builtin_amdgcn_mfma_f32_32x32x16_bf16(
        wfrag(WL, cq * 32 + ln, kc, lh), bfB[kc], acc, 0, 0, 0);
  float sab = 0.f;
#pragma unroll
  for (int r = 0; r < 16; ++r) sab += fabsf(acc[r]);
  sab += __shfl_xor(sab, 32);
  if (l < 32) rowpart[w][ln] = sab;
  __syncthreads();  // also: all WL(T) reads done
  const float rsum =
      rowpart[0][ln] + rowpart[1][ln] + rowpart[2][ln] + rowpart[3][ln];
  const float rinv = 1.f / fmaxf(rsum, EPSN);
  float basen[16];
#pragma unroll
  for (int r = 0; r < 16; ++r) basen[r] = acc[r] * rinv;

  // ---- mT -> Mb
  stageW(Wmb, WL, t);
  __syncthreads();
#pragma unroll
  for (int r = 0; r < 16; ++r) acc[r] = 0.f;
#pragma unroll
  for (int kc = 0; kc < 8; ++kc)
    acc = __builtin_amdgcn_mfma_f32_32x32x16_bf16(
        wfrag(WL, cq * 32 + ln, kc, lh), bfA[kc], acc, 0, 0, 0);
#pragma unroll
  for (int r = 0; r < 16; ++r) {
    int c = cq * 32 + (r & 3) + 8 * (r >> 2) + 4 * lh;
    Mb[ln][(((c >> 3) ^ (ln & 15)) << 3) + (c & 7)] = f2b(acc[r] + blds[0][c]);
  }
  __syncthreads();

  // ---- sT -> Sb
  stageW(Wsb, WL, t);
  __syncthreads();
#pragma unroll
  for (int r = 0; r < 16; ++r) acc[r] = 0.f;
#pragma unroll
  for (int kc = 0; kc < 8; ++kc)
    acc = __builtin_amdgcn_mfma_f32_32x32x16_bf16(
        wfrag(WL, cq * 32 + ln, kc, lh), bfS[kc], acc, 0, 0, 0);
#pragma unroll
  for (int r = 0; r < 16; ++r) {
    int c = cq * 32 + (r & 3) + 8 * (r >> 2) + 4 * lh;
    Sb[ln][(((c >> 3) ^ (ln & 15)) << 3) + (c & 7)] = f2b(acc[r] + blds[1][c]);
  }
  __syncthreads();

  // ---- zT = Wg1*m + Wg2*s
  stageW(Wg1b, WL, t);
  __syncthreads();
#pragma unroll
  for (int r = 0; r < 16; ++r) acc[r] = 0.f;
#pragma unroll
  for (int kc = 0; kc < 8; ++kc)
    acc = __builtin_amdgcn_mfma_f32_32x32x16_bf16(
        wfrag(WL, cq * 32 + ln, kc, lh), wfrag(Mb, ln, kc, lh), acc, 0, 0, 0);
  __syncthreads();
  stageW(Wg2b, WL, t);
  __syncthreads();
#pragma unroll
  for (int kc = 0; kc < 8; ++kc)
    acc = __builtin_amdgcn_mfma_f32_32x32x16_bf16(
        wfrag(WL, cq * 32 + ln, kc, lh), wfrag(Sb, ln, kc, lh), acc, 0, 0, 0);

  // ---- gate epilogue
  float val[16];
#pragma unroll
  for (int r = 0; r < 16; ++r) {
    int c = cq * 32 + (r & 3) + 8 * (r >> 2) + 4 * lh;
    float z = acc[r] + blds[2][c];
    float g = 1.f / (1.f + __expf(-z));
    int off = (((c >> 3) ^ (ln & 15)) << 3) + (c & 7);
    float mv = b2f(Mb[ln][off]);
    float sv = b2f(Sb[ln][off]);
    val[r] = basen[r] + g * mv + (1.f - g) * sv;
  }

  // ---- transposed coalesced stores (tr aliases Mb/Sb; vals are in regs)
  const int orow = t >> 3, c0 = (t & 7) * 4;
  if (outNorm) {
    __syncthreads();
#pragma unroll
    for (int r = 0; r < 16; ++r)
      tr[ln][cq * 32 + (r & 3) + 8 * (r >> 2) + 4 * lh] = basen[r];
    __syncthreads();
#pragma unroll
    for (int q = 0; q < 4; ++q)
      *(float4*)&outNorm[(size_t)(i0 + orow) * DD + c0 + 32 * q] =
          *(const float4*)&tr[orow][c0 + 32 * q];
  }
  __syncthreads();
#pragma unroll
  for (int r = 0; r < 16; ++r)
    tr[ln][cq * 32 + (r & 3) + 8 * (r >> 2) + 4 * lh] = val[r];
  __syncthreads();
  if (outValF) {
#pragma unroll
    for (int q = 0; q < 4; ++q)
      *(float4*)&outValF[(size_t)(i0 + orow) * DD + c0 + 32 * q] =
          *(const float4*)&tr[orow][c0 + 32 * q];
  }
  if (outValB) {
#pragma unroll
    for (int q = 0; q < 4; ++q) {
      float4 v = *(const float4*)&tr[orow][c0 + 32 * q];
      ushort4 o;
      o.x = f2b(v.x); o.y = f2b(v.y); o.z = f2b(v.z); o.w = f2b(v.w);
      *(ushort4*)&outValB[(size_t)(i0 + orow) * DD + c0 + 32 * q] = o;
    }
  }
}

// ---------------------------------------------------------------------------
extern "C" void kernel_launch(void* const* d_in, const int* in_sizes, int n_in,
                              void* d_out, int out_size, void* d_ws,
                              size_t ws_size, hipStream_t stream) {
  const float* f1 = (const float*)d_in[0];
  const float* f2 = (const float*)d_in[1];
  const float* Wd1 = (const float*)d_in[2];
  const float* bd1 = (const float*)d_in[3];
  const float* Wd2 = (const float*)d_in[4];
  const float* bd2 = (const float*)d_in[5];
  const float* Ws1 = (const float*)d_in[6];
  const float* bs1 = (const float*)d_in[7];
  const float* Ws2 = (const float*)d_in[8];
  const float* bs2 = (const float*)d_in[9];
  const float* g1W1 = (const float*)d_in[10];
  const float* g1b1 = (const float*)d_in[11];
  const float* g1W2 = (const float*)d_in[12];
  const float* g1b2 = (const float*)d_in[13];
  const float* g2W1 = (const float*)d_in[14];
  const float* g2b1 = (const float*)d_in[15];
  const float* g2W2 = (const float*)d_in[16];
  const float* g2b2 = (const float*)d_in[17];

  const int N = in_sizes[0] / DD;  // 8192
  const size_t ND = (size_t)N * DD;

  float* ws = (float*)d_ws;
  float* T1 = ws;
  float* T2 = T1 + DD * DD;
  float* HA = T2 + DD * DD;             // N*D fp32
  float* rb = HA + ND;                  // N
  unsigned short* f1bb = (unsigned short*)(rb + N);
  unsigned short* f2bb = f1bb + ND;
  unsigned short* f1nb = f2bb + ND;
  unsigned short* T1b = f1nb + ND;
  unsigned short* T2b = T1b + DD * DD;
  unsigned short* Wb0 = T2b + DD * DD;  // 8 bf16 weight mats
  unsigned short* Wb1 = Wb0 + DD * DD;
  unsigned short* Wb2 = Wb1 + DD * DD;
  unsigned short* Wb3 = Wb2 + DD * DD;
  unsigned short* Wb4 = Wb3 + DD * DD;
  unsigned short* Wb5 = Wb4 + DD * DD;
  unsigned short* Wb6 = Wb5 + DD * DD;
  unsigned short* Wb7 = Wb6 + DD * DD;
  float* out0 = (float*)d_out;
  float* out1 = out0 + ND;

  const int cvtGrid = (int)((ND / 4 + 255) / 256);
  const int wGrid = (DD * DD / 4 + 255) / 256;
  k_cvt<<<cvtGrid, 256, 0, stream>>>(f1, f1bb, (int)(ND / 4));
  k_cvt<<<cvtGrid, 256, 0, stream>>>(f2, f2bb, (int)(ND / 4));
  k_cvt<<<wGrid, 256, 0, stream>>>(Wd1, Wb0, DD * DD / 4);
  k_cvt<<<wGrid, 256, 0, stream>>>(Ws1, Wb1, DD * DD / 4);
  k_cvt<<<wGrid, 256, 0, stream>>>(g1W1, Wb2, DD * DD / 4);
  k_cvt<<<wGrid, 256, 0, stream>>>(g1W2, Wb3, DD * DD / 4);
  k_cvt<<<wGrid, 256, 0, stream>>>(Wd2, Wb4, DD * DD / 4);
  k_cvt<<<wGrid, 256, 0, stream>>>(Ws2, Wb5, DD * DD / 4);
  k_cvt<<<wGrid, 256, 0, stream>>>(g2W1, Wb6, DD * DD / 4);
  k_cvt<<<wGrid, 256, 0, stream>>>(g2W2, Wb7, DD * DD / 4);

  // two-hop Gram matrices
  hipMemsetAsync(T1, 0, sizeof(float) * 2 * DD * DD, stream);
  k_ata<<<dim3(2, 2, 64), 256, 0, stream>>>(f1, T1, N / 64);
  k_ata<<<dim3(2, 2, 64), 256, 0, stream>>>(f2, T2, N / 64);
  k_cvt<<<wGrid, 256, 0, stream>>>(T1, T1b, DD * DD / 4);
  k_cvt<<<wGrid, 256, 0, stream>>>(T2, T2b, DD * DD / 4);

  // --- message block 1: d2 -> d1 ---
  hipMemsetAsync(HA, 0, sizeof(float) * (ND + N), stream);
  k_attn<<<dim3(N / 64, JSPLIT), 256, 0, stream>>>(f1bb, f2bb, HA, rb, N);
  k_post<<<N / 32, 256, 0, stream>>>(HA, rb, f2bb, f1bb, T1b, Wb0, bd1, Wb1,
                                     bs1, Wb2, g1b1, Wb3, g1b2, out0, nullptr,
                                     f1nb, N);

  // --- message block 2: d1 -> d2 ---
  hipMemsetAsync(HA, 0, sizeof(float) * (ND + N), stream);
  k_attn<<<dim3(N / 64, JSPLIT), 256, 0, stream>>>(f2bb, f1nb, HA, rb, N);
  k_post<<<N / 32, 256, 0, stream>>>(HA, rb, f1nb, f2bb, T2b, Wb4, bd2, Wb5,
                                     bs2, Wb6, g2b1, Wb7, g2b2, nullptr, out1,
                                     nullptr, N);
}

// Round 4
// 248.362 us; speedup vs baseline: 6.3885x; 1.1122x over previous
//
#include <hip/hip_runtime.h>
#include <hip/hip_bf16.h>

#define DD 128
#define EPSN 1e-12f

typedef __attribute__((ext_vector_type(8))) short bf16x8;
typedef __attribute__((ext_vector_type(16))) float f32x16;

__device__ __forceinline__ unsigned short f2b(float f) {
  unsigned int u = __builtin_bit_cast(unsigned int, f);
  return (unsigned short)((u + 0x7fffu + ((u >> 16) & 1u)) >> 16);
}
__device__ __forceinline__ float b2f(unsigned short u) {
  unsigned int v = ((unsigned int)u) << 16;
  return __builtin_bit_cast(float, v);
}

// ---------------------------------------------------------------------------
// fp32 -> bf16: two big tensors (f1, f2).  grid(n4/256, 2)
// ---------------------------------------------------------------------------
__global__ __launch_bounds__(256) void k_cvt2(const float* __restrict__ a,
                                              const float* __restrict__ b,
                                              unsigned short* __restrict__ da,
                                              unsigned short* __restrict__ db,
                                              int n4) {
  int i = blockIdx.x * 256 + threadIdx.x;
  const float* s = blockIdx.y ? b : a;
  unsigned short* d = blockIdx.y ? db : da;
  if (i < n4) {
    float4 v = ((const float4*)s)[i];
    ushort4 o;
    o.x = f2b(v.x); o.y = f2b(v.y); o.z = f2b(v.z); o.w = f2b(v.w);
    ((ushort4*)d)[i] = o;
  }
}

// ---------------------------------------------------------------------------
// fp32 -> bf16: ten DxD matrices in one dispatch.  grid(16, 10)
// ---------------------------------------------------------------------------
__global__ __launch_bounds__(256) void k_cvt10(
    const float* __restrict__ s0, const float* __restrict__ s1,
    const float* __restrict__ s2, const float* __restrict__ s3,
    const float* __restrict__ s4, const float* __restrict__ s5,
    const float* __restrict__ s6, const float* __restrict__ s7,
    const float* __restrict__ s8, const float* __restrict__ s9,
    unsigned short* __restrict__ d0, unsigned short* __restrict__ d1,
    unsigned short* __restrict__ d2, unsigned short* __restrict__ d3,
    unsigned short* __restrict__ d4, unsigned short* __restrict__ d5,
    unsigned short* __restrict__ d6, unsigned short* __restrict__ d7,
    unsigned short* __restrict__ d8, unsigned short* __restrict__ d9) {
  int i = blockIdx.x * 256 + threadIdx.x;  // 0..4095 = DD*DD/4
  const float* s;
  unsigned short* d;
  switch (blockIdx.y) {
    case 0: s = s0; d = d0; break;
    case 1: s = s1; d = d1; break;
    case 2: s = s2; d = d2; break;
    case 3: s = s3; d = d3; break;
    case 4: s = s4; d = d4; break;
    case 5: s = s5; d = d5; break;
    case 6: s = s6; d = d6; break;
    case 7: s = s7; d = d7; break;
    case 8: s = s8; d = d8; break;
    default: s = s9; d = d9; break;
  }
  float4 v = ((const float4*)s)[i];
  ushort4 o;
  o.x = f2b(v.x); o.y = f2b(v.y); o.z = f2b(v.z); o.w = f2b(v.w);
  ((ushort4*)d)[i] = o;
}

// ---------------------------------------------------------------------------
// T = X^T X  (D x D, symmetric), atomic-accumulated.  grid(2,2,64) x 256
// ---------------------------------------------------------------------------
__global__ __launch_bounds__(256) void k_ata(const float* __restrict__ X,
                                             float* __restrict__ T,
                                             int chunkRows) {
  __shared__ float si[128][64];
  __shared__ float sj[128][64];
  const int bi = blockIdx.x, bj = blockIdx.y;
  const int n0 = blockIdx.z * chunkRows;
  const int t = threadIdx.x;
  for (int idx = t; idx < 128 * 16; idx += 256) {
    int r = idx >> 4, c4 = idx & 15;
    float4 a = *((const float4*)(X + (size_t)(n0 + r) * DD + bi * 64) + c4);
    float4 b = *((const float4*)(X + (size_t)(n0 + r) * DD + bj * 64) + c4);
    *(float4*)&si[r][c4 * 4] = a;
    *(float4*)&sj[r][c4 * 4] = b;
  }
  __syncthreads();
  const int tx = t & 15, ty = t >> 4;
  float acc[4][4] = {};
  for (int n = 0; n < 128; ++n) {
    float4 av = *(const float4*)&si[n][ty * 4];
    float4 bv = *(const float4*)&sj[n][tx * 4];
    float a[4] = {av.x, av.y, av.z, av.w};
    float b[4] = {bv.x, bv.y, bv.z, bv.w};
#pragma unroll
    for (int i = 0; i < 4; ++i)
#pragma unroll
      for (int j = 0; j < 4; ++j) acc[i][j] += a[i] * b[j];
  }
#pragma unroll
  for (int i = 0; i < 4; ++i)
#pragma unroll
    for (int j = 0; j < 4; ++j)
      atomicAdd(&T[(size_t)(bi * 64 + ty * 4 + i) * DD + bj * 64 + tx * 4 + j],
                acc[i][j]);
}

// ---------------------------------------------------------------------------
// MFMA fused attention, LDS-traffic-minimized:
//  - X row-fragments hoisted to registers (loop-invariant)
//  - ph1 operand-swapped: lane holds S-row i; diag/rowabs per-lane
//  - S -> ph2 A-operand in-register (cvt_pk + permlane32_swap), no Ss LDS
//  - Y staged row-major (ph1) + [j/4][d/16][4][16] subtiles, 160B-padded
//    XOR-swizzled blocks (ph2 B via ds_read_b64_tr_b16, conflict-free)
// grid(N/64, JSPLIT) x 256.
// ---------------------------------------------------------------------------
#define JSPLIT 8
__global__ __launch_bounds__(256, 2) void k_attn(
    const unsigned short* __restrict__ Xb, const unsigned short* __restrict__ Yb,
    float* __restrict__ HA, float* __restrict__ rabs, int N) {
  __shared__ unsigned short Ys[64][128];     // 16KB, chunk-XOR row-major
  __shared__ unsigned short YstU[128 * 80];  // 20KB, tr-read subtiles
  const int t = threadIdx.x;
  const int w = t >> 6, l = t & 63, lh = l >> 5, ln = l & 31;
  const int wb = w >> 1, jh = w & 1;
  const int i0 = blockIdx.x * 64;
  const int jbase = blockIdx.y * (N / JSPLIT);
  const int jiters = (N / JSPLIT) / 64;

  // X fragments in registers: lane ln -> row i0+wb*32+ln, k = kc*16+lh*8+e
  const int xrow = i0 + wb * 32 + ln;
  bf16x8 xf[8];
#pragma unroll
  for (int kc = 0; kc < 8; ++kc)
    xf[kc] = *(const bf16x8*)(Xb + (size_t)xrow * DD + kc * 16 + lh * 8);

  f32x16 acc2[4];
#pragma unroll
  for (int cb = 0; cb < 4; ++cb)
#pragma unroll
    for (int r = 0; r < 16; ++r) acc2[cb][r] = 0.f;
  float rsum = 0.f;

  const int sj = t >> 4;  // staging: j = r*16 + sj, d-chunk = d8
  const int d8 = t & 15;

  bf16x8 rg[4];
  {
    const unsigned short* yb = Yb + (size_t)(jbase + sj) * DD + d8 * 8;
#pragma unroll
    for (int r = 0; r < 4; ++r)
      rg[r] = *(const bf16x8*)(yb + (size_t)(r * 16) * DD);
  }

  const unsigned ystBase = (unsigned)(size_t)&YstU[0];
  const int d4b = ln >> 4;
  const int xrb = (ln & 15) << 1;

  for (int jt = 0; jt < jiters; ++jt) {
    __syncthreads();  // previous iter's readers done
    // ---- write staged regs -> Ys (row-major) + YstU (tr subtiles)
#pragma unroll
    for (int r = 0; r < 4; ++r) {
      int j = r * 16 + sj;
      *(bf16x8*)&Ys[j][((d8 ^ (j & 15)) << 3)] = rg[r];
      int B = j >> 2;
      int blk = B * 8 + ((d8 >> 1) ^ (B & 7));
      int eoff = 80 * blk + (j & 3) * 16 + (((d8 & 1) ^ (B & 1)) << 3);
      *(bf16x8*)&YstU[eoff] = rg[r];
    }
    __syncthreads();
    // ---- T14: prefetch next Y tile into regs (consumed next iter)
    if (jt + 1 < jiters) {
      const unsigned short* yb =
          Yb + (size_t)(jbase + (jt + 1) * 64 + sj) * DD + d8 * 8;
#pragma unroll
      for (int r = 0; r < 4; ++r)
        rg[r] = *(const bf16x8*)(yb + (size_t)(r * 16) * DD);
    }
    // ---- ph1 (swapped): lane ln holds S-row i, j spread over (r,lh)
    const int yr = jh * 32 + ln;
    f32x16 s;
#pragma unroll
    for (int r = 0; r < 16; ++r) s[r] = 0.f;
#pragma unroll
    for (int kc = 0; kc < 8; ++kc) {
      int ck = kc * 2 + lh;
      bf16x8 yv = *(const bf16x8*)&Ys[yr][((ck ^ (yr & 15)) << 3)];
      s = __builtin_amdgcn_mfma_f32_32x32x16_bf16(yv, xf[kc], s, 0, 0, 0);
    }
    // ---- diag zero (tile-on-diagonal only)
    const int j0g = jbase + jt * 64 + jh * 32;
    if (i0 + wb * 32 == j0g) {
#pragma unroll
      for (int r = 0; r < 16; ++r) {
        int jl = (r & 3) + 8 * (r >> 2) + 4 * lh;
        if (jl == ln) s[r] = 0.f;
      }
    }
    // ---- rowabs (lane-local row!)
#pragma unroll
    for (int r = 0; r < 16; ++r) rsum += fabsf(s[r]);
    // ---- issue ph2 B tr-reads (latency hidden under pack VALU)
    uint2 tvv[2][4][2];
#pragma unroll
    for (int f = 0; f < 2; ++f)
#pragma unroll
      for (int h2 = 0; h2 < 2; ++h2) {
        const int B = jh * 8 + f * 4 + lh * 2 + h2;
        const int b7 = B & 7;
        const unsigned xr2 = (unsigned)(xrb ^ (h2 << 4));
#pragma unroll
        for (int cb = 0; cb < 4; ++cb) {
          int blk = B * 8 + ((cb * 2 + d4b) ^ b7);
          unsigned a = ystBase + (unsigned)(blk * 160) + xr2;
          asm volatile("ds_read_b64_tr_b16 %0, %1"
                       : "=v"(tvv[f][cb][h2])
                       : "v"(a));
        }
      }
    // ---- pack S row to bf16 fragments (cvt_pk + permlane32_swap)
    unsigned pq[8];
#pragma unroll
    for (int q = 0; q < 8; ++q)
      asm("v_cvt_pk_bf16_f32 %0, %1, %2"
          : "=v"(pq[q])
          : "v"(s[2 * q]), "v"(s[2 * q + 1]));
    bf16x8 av2[2];
#pragma unroll
    for (int f = 0; f < 2; ++f) {
      unsigned a0 = pq[4 * f + 0], b0 = pq[4 * f + 2];
      unsigned a1 = pq[4 * f + 1], b1 = pq[4 * f + 3];
      asm volatile("v_permlane32_swap_b32 %0, %1" : "+v"(a0), "+v"(b0));
      asm volatile("v_permlane32_swap_b32 %0, %1" : "+v"(a1), "+v"(b1));
      av2[f] = __builtin_bit_cast(bf16x8, make_uint4(a0, a1, b0, b1));
    }
    // ---- drain tr reads, fence, then ph2 MFMAs (rule #18)
    asm volatile("s_waitcnt lgkmcnt(0)" ::: "memory");
    __builtin_amdgcn_sched_barrier(0);
#pragma unroll
    for (int f = 0; f < 2; ++f)
#pragma unroll
      for (int cb = 0; cb < 4; ++cb) {
        bf16x8 bv = __builtin_bit_cast(
            bf16x8, make_uint4(tvv[f][cb][0].x, tvv[f][cb][0].y,
                               tvv[f][cb][1].x, tvv[f][cb][1].y));
        acc2[cb] =
            __builtin_amdgcn_mfma_f32_32x32x16_bf16(av2[f], bv, acc2[cb], 0, 0, 0);
      }
  }
  // ---- epilogue
  rsum += __shfl_xor(rsum, 32);
  if (l < 32) atomicAdd(&rabs[i0 + wb * 32 + ln], rsum);
#pragma unroll
  for (int cb = 0; cb < 4; ++cb)
#pragma unroll
    for (int r = 0; r < 16; ++r) {
      int row = i0 + wb * 32 + (r & 3) + 8 * (r >> 2) + 4 * lh;
      int d = cb * 32 + ln;
      atomicAdd(&HA[(size_t)row * DD + d], acc2[cb][r]);
    }
}

// ---------------------------------------------------------------------------
// Fused post-attention chain (unchanged from R2 — passes).
// ---------------------------------------------------------------------------
__device__ __forceinline__ void stageW(const unsigned short* __restrict__ g,
                                       unsigned short (*L)[128], int t) {
#pragma unroll
  for (int idx = t; idx < 2048; idx += 256) {
    int r = idx >> 4, ch = idx & 15;
    *(bf16x8*)&L[r][(ch ^ (r & 15)) << 3] = *(const bf16x8*)(g + r * 128 + ch * 8);
  }
}
__device__ __forceinline__ bf16x8 wfrag(const unsigned short (*L)[128], int row,
                                        int kc, int lh) {
  int ch = kc * 2 + lh;
  return *(const bf16x8*)&L[row][(ch ^ (row & 15)) << 3];
}

__global__ __launch_bounds__(256) void k_post(
    const float* __restrict__ HA, const float* __restrict__ rb,
    const unsigned short* __restrict__ fselfb,
    const unsigned short* __restrict__ fbaseb,
    const unsigned short* __restrict__ Tb,
    const unsigned short* __restrict__ Wmb, const float* __restrict__ bm,
    const unsigned short* __restrict__ Wsb, const float* __restrict__ bs,
    const unsigned short* __restrict__ Wg1b, const float* __restrict__ bg1,
    const unsigned short* __restrict__ Wg2b, const float* __restrict__ bg2,
    float* __restrict__ outNorm, float* __restrict__ outValF,
    unsigned short* __restrict__ outValB, int N) {
  __shared__ unsigned short WL[128][128];
  __shared__ __align__(16) char pool[32 * 132 * 4];
  __shared__ float blds[3][128];
  __shared__ float rowpart[4][32];
  unsigned short(*Mb)[128] = (unsigned short(*)[128])pool;
  unsigned short(*Sb)[128] = (unsigned short(*)[128])(pool + 8192);
  float(*tr)[132] = (float(*)[132])pool;

  const int t = threadIdx.x;
  const int w = t >> 6, l = t & 63, ln = l & 31, lh = l >> 5;
  const int i0 = blockIdx.x * 32;
  const int row = i0 + ln;
  const int cq = w;

  const float sc = (1.f / (float)N) / fmaxf(rb[row], EPSN);
  bf16x8 bfA[8], bfS[8], bfB[8];
#pragma unroll
  for (int kc = 0; kc < 8; ++kc) {
    const float* hp = HA + (size_t)row * DD + kc * 16 + lh * 8;
    float4 u = *(const float4*)hp;
    float4 v = *(const float4*)(hp + 4);
    bf16x8 a;
    a[0] = (short)f2b(u.x * sc); a[1] = (short)f2b(u.y * sc);
    a[2] = (short)f2b(u.z * sc); a[3] = (short)f2b(u.w * sc);
    a[4] = (short)f2b(v.x * sc); a[5] = (short)f2b(v.y * sc);
    a[6] = (short)f2b(v.z * sc); a[7] = (short)f2b(v.w * sc);
    bfA[kc] = a;
    bfS[kc] = *(const bf16x8*)(fselfb + (size_t)row * DD + kc * 16 + lh * 8);
    bfB[kc] = *(const bf16x8*)(fbaseb + (size_t)row * DD + kc * 16 + lh * 8);
  }
  if (t < 128) {
    blds[0][t] = bm[t];
    blds[1][t] = bs[t];
    blds[2][t] = bg1[t] + bg2[t];
  }
  stageW(Tb, WL, t);
  __syncthreads();

  f32x16 acc;
#pragma unroll
  for (int r = 0; r < 16; ++r) acc[r] = 0.f;
#pragma unroll
  for (int kc = 0; kc < 8; ++kc)
    acc = __builtin_amdgcn_mfma_f32_32x32x16_bf16(
        wfrag(WL, cq * 32 + ln, kc, lh), bfB[kc], acc, 0, 0, 0);
  float sab = 0.f;
#pragma unroll
  for (int r = 0; r < 16; ++r) sab += fabsf(acc[r]);
  sab += __shfl_xor(sab, 32);
  if (l < 32) rowpart[w][ln] = sab;
  __syncthreads();
  const float rsum =
      rowpart[0][ln] + rowpart[1][ln] + rowpart[2][ln] + rowpart[3][ln];
  const float rinv = 1.f / fmaxf(rsum, EPSN);
  float basen[16];
#pragma unroll
  for (int r = 0; r < 16; ++r) basen[r] = acc[r] * rinv;

  stageW(Wmb, WL, t);
  __syncthreads();
#pragma unroll
  for (int r = 0; r < 16; ++r) acc[r] = 0.f;
#pragma unroll
  for (int kc = 0; kc < 8; ++kc)
    acc = __builtin_amdgcn_mfma_f32_32x32x16_bf16(
        wfrag(WL, cq * 32 + ln, kc, lh), bfA[kc], acc, 0, 0, 0);
#pragma unroll
  for (int r = 0; r < 16; ++r) {
    int c = cq * 32 + (r & 3) + 8 * (r >> 2) + 4 * lh;
    Mb[ln][(((c >> 3) ^ (ln & 15)) << 3) + (c & 7)] = f2b(acc[r] + blds[0][c]);
  }
  __syncthreads();

  stageW(Wsb, WL, t);
  __syncthreads();
#pragma unroll
  for (int r = 0; r < 16; ++r) acc[r] = 0.f;
#pragma unroll
  for (int kc = 0; kc < 8; ++kc)
    acc = __builtin_amdgcn_mfma_f32_32x32x16_bf16(
        wfrag(WL, cq * 32 + ln, kc, lh), bfS[kc], acc, 0, 0, 0);
#pragma unroll
  for (int r = 0; r < 16; ++r) {
    int c = cq * 32 + (r & 3) + 8 * (r >> 2) + 4 * lh;
    Sb[ln][(((c >> 3) ^ (ln & 15)) << 3) + (c & 7)] = f2b(acc[r] + blds[1][c]);
  }
  __syncthreads();

  stageW(Wg1b, WL, t);
  __syncthreads();
#pragma unroll
  for (int r = 0; r < 16; ++r) acc[r] = 0.f;
#pragma unroll
  for (int kc = 0; kc < 8; ++kc)
    acc = __builtin_amdgcn_mfma_f32_32x32x16_bf16(
        wfrag(WL, cq * 32 + ln, kc, lh), wfrag(Mb, ln, kc, lh), acc, 0, 0, 0);
  __syncthreads();
  stageW(Wg2b, WL, t);
  __syncthreads();
#pragma unroll
  for (int kc = 0; kc < 8; ++kc)
    acc = __builtin_amdgcn_mfma_f32_32x32x16_bf16(
        wfrag(WL, cq * 32 + ln, kc, lh), wfrag(Sb, ln, kc, lh), acc, 0, 0, 0);

  float val[16];
#pragma unroll
  for (int r = 0; r < 16; ++r) {
    int c = cq * 32 + (r & 3) + 8 * (r >> 2) + 4 * lh;
    float z = acc[r] + blds[2][c];
    float g = 1.f / (1.f + __expf(-z));
    int off = (((c >> 3) ^ (ln & 15)) << 3) + (c & 7);
    float mv = b2f(Mb[ln][off]);
    float sv = b2f(Sb[ln][off]);
    val[r] = basen[r] + g * mv + (1.f - g) * sv;
  }

  const int orow = t >> 3, c0 = (t & 7) * 4;
  if (outNorm) {
    __syncthreads();
#pragma unroll
    for (int r = 0; r < 16; ++r)
      tr[ln][cq * 32 + (r & 3) + 8 * (r >> 2) + 4 * lh] = basen[r];
    __syncthreads();
#pragma unroll
    for (int q = 0; q < 4; ++q)
      *(float4*)&outNorm[(size_t)(i0 + orow) * DD + c0 + 32 * q] =
          *(const float4*)&tr[orow][c0 + 32 * q];
  }
  __syncthreads();
#pragma unroll
  for (int r = 0; r < 16; ++r)
    tr[ln][cq * 32 + (r & 3) + 8 * (r >> 2) + 4 * lh] = val[r];
  __syncthreads();
  if (outValF) {
#pragma unroll
    for (int q = 0; q < 4; ++q)
      *(float4*)&outValF[(size_t)(i0 + orow) * DD + c0 + 32 * q] =
          *(const float4*)&tr[orow][c0 + 32 * q];
  }
  if (outValB) {
#pragma unroll
    for (int q = 0; q < 4; ++q) {
      float4 v = *(const float4*)&tr[orow][c0 + 32 * q];
      ushort4 o;
      o.x = f2b(v.x); o.y = f2b(v.y); o.z = f2b(v.z); o.w = f2b(v.w);
      *(ushort4*)&outValB[(size_t)(i0 + orow) * DD + c0 + 32 * q] = o;
    }
  }
}

// ---------------------------------------------------------------------------
extern "C" void kernel_launch(void* const* d_in, const int* in_sizes, int n_in,
                              void* d_out, int out_size, void* d_ws,
                              size_t ws_size, hipStream_t stream) {
  const float* f1 = (const float*)d_in[0];
  const float* f2 = (const float*)d_in[1];
  const float* Wd1 = (const float*)d_in[2];
  const float* bd1 = (const float*)d_in[3];
  const float* Wd2 = (const float*)d_in[4];
  const float* bd2 = (const float*)d_in[5];
  const float* Ws1 = (const float*)d_in[6];
  const float* bs1 = (const float*)d_in[7];
  const float* Ws2 = (const float*)d_in[8];
  const float* bs2 = (const float*)d_in[9];
  const float* g1W1 = (const float*)d_in[10];
  const float* g1b1 = (const float*)d_in[11];
  const float* g1W2 = (const float*)d_in[12];
  const float* g1b2 = (const float*)d_in[13];
  const float* g2W1 = (const float*)d_in[14];
  const float* g2b1 = (const float*)d_in[15];
  const float* g2W2 = (const float*)d_in[16];
  const float* g2b2 = (const float*)d_in[17];

  const int N = in_sizes[0] / DD;  // 8192
  const size_t ND = (size_t)N * DD;

  float* ws = (float*)d_ws;
  float* T1 = ws;
  float* T2 = T1 + DD * DD;
  float* HA = T2 + DD * DD;             // N*D fp32
  float* rb = HA + ND;                  // N
  unsigned short* f1bb = (unsigned short*)(rb + N);
  unsigned short* f2bb = f1bb + ND;
  unsigned short* f1nb = f2bb + ND;
  unsigned short* T1b = f1nb + ND;
  unsigned short* T2b = T1b + DD * DD;
  unsigned short* Wb0 = T2b + DD * DD;
  unsigned short* Wb1 = Wb0 + DD * DD;
  unsigned short* Wb2 = Wb1 + DD * DD;
  unsigned short* Wb3 = Wb2 + DD * DD;
  unsigned short* Wb4 = Wb3 + DD * DD;
  unsigned short* Wb5 = Wb4 + DD * DD;
  unsigned short* Wb6 = Wb5 + DD * DD;
  unsigned short* Wb7 = Wb6 + DD * DD;
  float* out0 = (float*)d_out;
  float* out1 = out0 + ND;

  // bf16 conversions (fused)
  k_cvt2<<<dim3((int)(ND / 4 / 256), 2), 256, 0, stream>>>(f1, f2, f1bb, f2bb,
                                                           (int)(ND / 4));

  // two-hop Gram matrices
  hipMemsetAsync(T1, 0, sizeof(float) * 2 * DD * DD, stream);
  k_ata<<<dim3(2, 2, 64), 256, 0, stream>>>(f1, T1, N / 64);
  k_ata<<<dim3(2, 2, 64), 256, 0, stream>>>(f2, T2, N / 64);
  k_cvt10<<<dim3(16, 10), 256, 0, stream>>>(Wd1, Ws1, g1W1, g1W2, Wd2, Ws2,
                                            g2W1, g2W2, T1, T2, Wb0, Wb1, Wb2,
                                            Wb3, Wb4, Wb5, Wb6, Wb7, T1b, T2b);

  // --- message block 1: d2 -> d1 ---
  hipMemsetAsync(HA, 0, sizeof(float) * (ND + N), stream);
  k_attn<<<dim3(N / 64, JSPLIT), 256, 0, stream>>>(f1bb, f2bb, HA, rb, N);
  k_post<<<N / 32, 256, 0, stream>>>(HA, rb, f2bb, f1bb, T1b, Wb0, bd1, Wb1,
                                     bs1, Wb2, g1b1, Wb3, g1b2, out0, nullptr,
                                     f1nb, N);

  // --- message block 2: d1 -> d2 ---
  hipMemsetAsync(HA, 0, sizeof(float) * (ND + N), stream);
  k_attn<<<dim3(N / 64, JSPLIT), 256, 0, stream>>>(f2bb, f1nb, HA, rb, N);
  k_post<<<N / 32, 256, 0, stream>>>(HA, rb, f1nb, f2bb, T2b, Wb4, bd2, Wb5,
                                     bs2, Wb6, g2b1, Wb7, g2b2, nullptr, out1,
                                     nullptr, N);
}

// Round 5
// 177.605 us; speedup vs baseline: 8.9336x; 1.3984x over previous
//
#include <hip/hip_runtime.h>
#include <hip/hip_bf16.h>

#define DD 128
#define EPSN 1e-12f
#define JSPLIT 8

typedef __attribute__((ext_vector_type(8))) short bf16x8;
typedef __attribute__((ext_vector_type(16))) float f32x16;

__device__ __forceinline__ unsigned short f2b(float f) {
  unsigned int u = __builtin_bit_cast(unsigned int, f);
  return (unsigned short)((u + 0x7fffu + ((u >> 16) & 1u)) >> 16);
}
__device__ __forceinline__ float b2f(unsigned short u) {
  unsigned int v = ((unsigned int)u) << 16;
  return __builtin_bit_cast(float, v);
}

// ---------------------------------------------------------------------------
// fp32 -> bf16: two big tensors (f1, f2).  grid(n4/256, 2)
// ---------------------------------------------------------------------------
__global__ __launch_bounds__(256) void k_cvt2(const float* __restrict__ a,
                                              const float* __restrict__ b,
                                              unsigned short* __restrict__ da,
                                              unsigned short* __restrict__ db,
                                              int n4) {
  int i = blockIdx.x * 256 + threadIdx.x;
  const float* s = blockIdx.y ? b : a;
  unsigned short* d = blockIdx.y ? db : da;
  if (i < n4) {
    float4 v = ((const float4*)s)[i];
    ushort4 o;
    o.x = f2b(v.x); o.y = f2b(v.y); o.z = f2b(v.z); o.w = f2b(v.w);
    ((ushort4*)d)[i] = o;
  }
}

// ---------------------------------------------------------------------------
// fp32 -> bf16: ten DxD matrices in one dispatch.  grid(16, 10)
// ---------------------------------------------------------------------------
__global__ __launch_bounds__(256) void k_cvt10(
    const float* __restrict__ s0, const float* __restrict__ s1,
    const float* __restrict__ s2, const float* __restrict__ s3,
    const float* __restrict__ s4, const float* __restrict__ s5,
    const float* __restrict__ s6, const float* __restrict__ s7,
    const float* __restrict__ s8, const float* __restrict__ s9,
    unsigned short* __restrict__ d0, unsigned short* __restrict__ d1,
    unsigned short* __restrict__ d2, unsigned short* __restrict__ d3,
    unsigned short* __restrict__ d4, unsigned short* __restrict__ d5,
    unsigned short* __restrict__ d6, unsigned short* __restrict__ d7,
    unsigned short* __restrict__ d8, unsigned short* __restrict__ d9) {
  int i = blockIdx.x * 256 + threadIdx.x;
  const float* s;
  unsigned short* d;
  switch (blockIdx.y) {
    case 0: s = s0; d = d0; break;
    case 1: s = s1; d = d1; break;
    case 2: s = s2; d = d2; break;
    case 3: s = s3; d = d3; break;
    case 4: s = s4; d = d4; break;
    case 5: s = s5; d = d5; break;
    case 6: s = s6; d = d6; break;
    case 7: s = s7; d = d7; break;
    case 8: s = s8; d = d8; break;
    default: s = s9; d = d9; break;
  }
  float4 v = ((const float4*)s)[i];
  ushort4 o;
  o.x = f2b(v.x); o.y = f2b(v.y); o.z = f2b(v.z); o.w = f2b(v.w);
  ((ushort4*)d)[i] = o;
}

// ---------------------------------------------------------------------------
// T = X^T X  (D x D, symmetric), atomic-accumulated.  grid(2,2,64) x 256
// ---------------------------------------------------------------------------
__global__ __launch_bounds__(256) void k_ata(const float* __restrict__ X,
                                             float* __restrict__ T,
                                             int chunkRows) {
  __shared__ float si[128][64];
  __shared__ float sj[128][64];
  const int bi = blockIdx.x, bj = blockIdx.y;
  const int n0 = blockIdx.z * chunkRows;
  const int t = threadIdx.x;
  for (int idx = t; idx < 128 * 16; idx += 256) {
    int r = idx >> 4, c4 = idx & 15;
    float4 a = *((const float4*)(X + (size_t)(n0 + r) * DD + bi * 64) + c4);
    float4 b = *((const float4*)(X + (size_t)(n0 + r) * DD + bj * 64) + c4);
    *(float4*)&si[r][c4 * 4] = a;
    *(float4*)&sj[r][c4 * 4] = b;
  }
  __syncthreads();
  const int tx = t & 15, ty = t >> 4;
  float acc[4][4] = {};
  for (int n = 0; n < 128; ++n) {
    float4 av = *(const float4*)&si[n][ty * 4];
    float4 bv = *(const float4*)&sj[n][tx * 4];
    float a[4] = {av.x, av.y, av.z, av.w};
    float b[4] = {bv.x, bv.y, bv.z, bv.w};
#pragma unroll
    for (int i = 0; i < 4; ++i)
#pragma unroll
      for (int j = 0; j < 4; ++j) acc[i][j] += a[i] * b[j];
  }
#pragma unroll
  for (int i = 0; i < 4; ++i)
#pragma unroll
    for (int j = 0; j < 4; ++j)
      atomicAdd(&T[(size_t)(bi * 64 + ty * 4 + i) * DD + bj * 64 + tx * 4 + j],
                acc[i][j]);
}

// ---------------------------------------------------------------------------
// MFMA fused attention, atomic-free:
//  - i-tile 128, 512 threads (8 waves = 4 row-groups x 2 j-halves), JSPLIT=8
//  - single LDS Y copy (tr-subtile layout), double-buffered; ph1 row-frags
//    and ph2 tr-read frags both served from it; one barrier per iter
//  - j-half H partials merged in LDS, stored as bf16 slice (plain stores)
//  - slices 0..5 -> Hps (ws); 6,7 -> Hx (output buffer, row-interleaved)
// grid(N/128, JSPLIT) x 512.
// ---------------------------------------------------------------------------
__global__ __launch_bounds__(512, 2) void k_attn(
    const unsigned short* __restrict__ Xb, const unsigned short* __restrict__ Yb,
    unsigned short* __restrict__ Hps, unsigned short* __restrict__ Hx,
    float* __restrict__ rabs, int N) {
  __shared__ __align__(16) char LP[65536];
  unsigned short* Yst = (unsigned short*)LP;  // [2][10240] tr-subtiles
  float* mrg = (float*)LP;                    // epilogue merge [4][32][128]
  const int t = threadIdx.x;
  const int w = t >> 6, l = t & 63, lh = l >> 5, ln = l & 31;
  const int wb = w >> 1, jh = w & 1;
  const int i0 = blockIdx.x * 128;
  const size_t ND = (size_t)N * DD;
  const int jbase = blockIdx.y * (N / JSPLIT);
  const int jiters = (N / JSPLIT) / 64;

  // X fragments in registers (loop-invariant)
  const int xrow = i0 + wb * 32 + ln;
  bf16x8 xf[8];
#pragma unroll
  for (int kc = 0; kc < 8; ++kc)
    xf[kc] = *(const bf16x8*)(Xb + (size_t)xrow * DD + kc * 16 + lh * 8);

  f32x16 acc2[4];
#pragma unroll
  for (int cb = 0; cb < 4; ++cb)
#pragma unroll
    for (int r = 0; r < 16; ++r) acc2[cb][r] = 0.f;
  float rsum = 0.f;

  // staging: thread t -> row sjj, chunks ch0, ch0+8
  const int sjj = t >> 3;
  const int ch0 = t & 7;
  const int SB = sjj >> 2;
  bf16x8 rg[2];
  {
    const unsigned short* yb = Yb + (size_t)(jbase + sjj) * DD + ch0 * 8;
    rg[0] = *(const bf16x8*)yb;
    rg[1] = *(const bf16x8*)(yb + 64);
  }
  // prologue write -> buf 0
#pragma unroll
  for (int c = 0; c < 2; ++c) {
    int ch = ch0 + 8 * c;
    int blk = SB * 8 + ((ch >> 1) ^ (SB & 7));
    int eoff = 80 * blk + (sjj & 3) * 16 + (((ch & 1) ^ (SB & 1)) << 3);
    *(bf16x8*)&Yst[eoff] = rg[c];
  }

  const unsigned ystBase0 = (unsigned)(size_t)Yst;
  const int d4b = ln >> 4;
  const int xrb = (ln & 15) << 1;
  const int yr = jh * 32 + ln;
  const int YB = yr >> 2;

  for (int jt = 0; jt < jiters; ++jt) {
    const int cur = jt & 1;
    __syncthreads();  // buf[cur] writes visible; prev readers done
    // T14: prefetch next Y tile into regs
    if (jt + 1 < jiters) {
      const unsigned short* yb =
          Yb + (size_t)(jbase + (jt + 1) * 64 + sjj) * DD + ch0 * 8;
      rg[0] = *(const bf16x8*)yb;
      rg[1] = *(const bf16x8*)(yb + 64);
    }
    // ---- ph1 (swapped): lane ln holds S-row i; two MFMA chains
    f32x16 s0, s1;
#pragma unroll
    for (int r = 0; r < 16; ++r) { s0[r] = 0.f; s1[r] = 0.f; }
#pragma unroll
    for (int kc = 0; kc < 8; ++kc) {
      int ck = kc * 2 + lh;
      int off = 80 * (YB * 8 + ((ck >> 1) ^ (YB & 7))) + (yr & 3) * 16 +
                (((ck & 1) ^ (YB & 1)) << 3);
      bf16x8 yv = *(const bf16x8*)&Yst[cur * 10240 + off];
      if (kc & 1)
        s1 = __builtin_amdgcn_mfma_f32_32x32x16_bf16(yv, xf[kc], s1, 0, 0, 0);
      else
        s0 = __builtin_amdgcn_mfma_f32_32x32x16_bf16(yv, xf[kc], s0, 0, 0, 0);
    }
    f32x16 s;
#pragma unroll
    for (int r = 0; r < 16; ++r) s[r] = s0[r] + s1[r];
    // ---- diag zero (tile-on-diagonal only)
    const int j0g = jbase + jt * 64 + jh * 32;
    if (i0 + wb * 32 == j0g) {
#pragma unroll
      for (int r = 0; r < 16; ++r) {
        int jl = (r & 3) + 8 * (r >> 2) + 4 * lh;
        if (jl == ln) s[r] = 0.f;
      }
    }
    // ---- rowabs (lane-local row)
#pragma unroll
    for (int r = 0; r < 16; ++r) rsum += fabsf(s[r]);
    // ---- issue ph2 B tr-reads
    const unsigned yB = ystBase0 + (unsigned)(cur * 20480);
    uint2 tvv[2][4][2];
#pragma unroll
    for (int f = 0; f < 2; ++f)
#pragma unroll
      for (int h2 = 0; h2 < 2; ++h2) {
        const int B = jh * 8 + f * 4 + lh * 2 + h2;
        const int b7 = B & 7;
        const unsigned xr2 = (unsigned)(xrb ^ (h2 << 4));
#pragma unroll
        for (int cb = 0; cb < 4; ++cb) {
          int blk = B * 8 + ((cb * 2 + d4b) ^ b7);
          unsigned a = yB + (unsigned)(blk * 160) + xr2;
          asm volatile("ds_read_b64_tr_b16 %0, %1"
                       : "=v"(tvv[f][cb][h2])
                       : "v"(a));
        }
      }
    // ---- pack S row to bf16 fragments (cvt_pk + permlane32_swap)
    unsigned pq[8];
#pragma unroll
    for (int q = 0; q < 8; ++q)
      asm("v_cvt_pk_bf16_f32 %0, %1, %2"
          : "=v"(pq[q])
          : "v"(s[2 * q]), "v"(s[2 * q + 1]));
    bf16x8 av2[2];
#pragma unroll
    for (int f = 0; f < 2; ++f) {
      unsigned a0 = pq[4 * f + 0], b0 = pq[4 * f + 2];
      unsigned a1 = pq[4 * f + 1], b1 = pq[4 * f + 3];
      asm volatile("v_permlane32_swap_b32 %0, %1" : "+v"(a0), "+v"(b0));
      asm volatile("v_permlane32_swap_b32 %0, %1" : "+v"(a1), "+v"(b1));
      av2[f] = __builtin_bit_cast(bf16x8, make_uint4(a0, a1, b0, b1));
    }
    // ---- drain tr reads, fence, ph2 MFMAs (rule #18)
    asm volatile("s_waitcnt lgkmcnt(0)" ::: "memory");
    __builtin_amdgcn_sched_barrier(0);
#pragma unroll
    for (int f = 0; f < 2; ++f)
#pragma unroll
      for (int cb = 0; cb < 4; ++cb) {
        bf16x8 bv = __builtin_bit_cast(
            bf16x8, make_uint4(tvv[f][cb][0].x, tvv[f][cb][0].y,
                               tvv[f][cb][1].x, tvv[f][cb][1].y));
        acc2[cb] =
            __builtin_amdgcn_mfma_f32_32x32x16_bf16(av2[f], bv, acc2[cb], 0, 0, 0);
      }
    // ---- write prefetched regs -> buf[cur^1]
    if (jt + 1 < jiters) {
      int bo = (cur ^ 1) * 10240;
#pragma unroll
      for (int c = 0; c < 2; ++c) {
        int ch = ch0 + 8 * c;
        int blk = SB * 8 + ((ch >> 1) ^ (SB & 7));
        int eoff = bo + 80 * blk + (sjj & 3) * 16 + (((ch & 1) ^ (SB & 1)) << 3);
        *(bf16x8*)&Yst[eoff] = rg[c];
      }
    }
  }
  // ---- epilogue: merge j-halves in LDS (reuse Yst), then bf16 stores
  __syncthreads();
  if (jh == 1) {
#pragma unroll
    for (int cb = 0; cb < 4; ++cb)
#pragma unroll
      for (int r = 0; r < 16; ++r) {
        int rl = (r & 3) + 8 * (r >> 2) + 4 * lh;
        mrg[wb * 4096 + rl * 128 + cb * 32 + ln] = acc2[cb][r];
      }
  }
  __syncthreads();
  if (jh == 0) {
    unsigned short* hp;
    int rstr;
    if (blockIdx.y < 6) {
      hp = Hps + (size_t)blockIdx.y * ND;
      rstr = 128;
    } else {
      hp = Hx + (blockIdx.y - 6) * 128;
      rstr = 256;
    }
#pragma unroll
    for (int cb = 0; cb < 4; ++cb)
#pragma unroll
      for (int r = 0; r < 16; ++r) {
        int rl = (r & 3) + 8 * (r >> 2) + 4 * lh;
        float v = acc2[cb][r] + mrg[wb * 4096 + rl * 128 + cb * 32 + ln];
        hp[(size_t)(i0 + wb * 32 + rl) * rstr + cb * 32 + ln] = f2b(v);
      }
  }
  rsum += __shfl_xor(rsum, 32);
  if (l < 32) atomicAdd(&rabs[i0 + wb * 32 + ln], rsum);
}

// ---------------------------------------------------------------------------
// Fused post-attention chain; A-input = sum of 8 bf16 H-partial slices
// (cooperatively reduced into LDS first).
// ---------------------------------------------------------------------------
__device__ __forceinline__ void stageW(const unsigned short* __restrict__ g,
                                       unsigned short (*L)[128], int t) {
#pragma unroll
  for (int idx = t; idx < 2048; idx += 256) {
    int r = idx >> 4, ch = idx & 15;
    *(bf16x8*)&L[r][(ch ^ (r & 15)) << 3] = *(const bf16x8*)(g + r * 128 + ch * 8);
  }
}
__device__ __forceinline__ bf16x8 wfrag(const unsigned short (*L)[128], int row,
                                        int kc, int lh) {
  int ch = kc * 2 + lh;
  return *(const bf16x8*)&L[row][(ch ^ (row & 15)) << 3];
}

__global__ __launch_bounds__(256) void k_post(
    const unsigned short* __restrict__ Hps, const unsigned short* __restrict__ Hx,
    const float* __restrict__ rb,
    const unsigned short* __restrict__ fselfb,
    const unsigned short* __restrict__ fbaseb,
    const unsigned short* __restrict__ Tb,
    const unsigned short* __restrict__ Wmb, const float* __restrict__ bm,
    const unsigned short* __restrict__ Wsb, const float* __restrict__ bs,
    const unsigned short* __restrict__ Wg1b, const float* __restrict__ bg1,
    const unsigned short* __restrict__ Wg2b, const float* __restrict__ bg2,
    float* __restrict__ outNorm, float* __restrict__ outValF,
    unsigned short* __restrict__ outValB, int N) {
  __shared__ unsigned short WL[128][128];
  __shared__ __align__(16) char pool[32 * 132 * 4];
  __shared__ float blds[3][128];
  __shared__ float rowpart[4][32];
  unsigned short(*Mb)[128] = (unsigned short(*)[128])pool;
  unsigned short(*Sb)[128] = (unsigned short(*)[128])(pool + 8192);
  float(*tr)[132] = (float(*)[132])pool;
  float(*hs)[132] = (float(*)[132])pool;

  const int t = threadIdx.x;
  const int w = t >> 6, l = t & 63, ln = l & 31, lh = l >> 5;
  const int i0 = blockIdx.x * 32;
  const int row = i0 + ln;
  const int cq = w;
  const size_t ND = (size_t)N * DD;

  // ---- cooperative 8-slice sum -> hs (f32)
  for (int idx = t; idx < 512; idx += 256) {
    int r = idx >> 4, c8 = idx & 15;
    float a8[8] = {0.f, 0.f, 0.f, 0.f, 0.f, 0.f, 0.f, 0.f};
#pragma unroll
    for (int sp = 0; sp < 8; ++sp) {
      const unsigned short* p =
          (sp < 6) ? Hps + (size_t)sp * ND + (size_t)(i0 + r) * DD + c8 * 8
                   : Hx + (size_t)(i0 + r) * 256 + (sp - 6) * 128 + c8 * 8;
      bf16x8 v = *(const bf16x8*)p;
#pragma unroll
      for (int e = 0; e < 8; ++e) a8[e] += b2f((unsigned short)v[e]);
    }
    *(float4*)&hs[r][c8 * 8] = make_float4(a8[0], a8[1], a8[2], a8[3]);
    *(float4*)&hs[r][c8 * 8 + 4] = make_float4(a8[4], a8[5], a8[6], a8[7]);
  }
  if (t < 128) {
    blds[0][t] = bm[t];
    blds[1][t] = bs[t];
    blds[2][t] = bg1[t] + bg2[t];
  }
  stageW(Tb, WL, t);
  __syncthreads();

  // ---- per-lane fragments
  const float sc = (1.f / (float)N) / fmaxf(rb[row], EPSN);
  bf16x8 bfA[8], bfS[8], bfB[8];
#pragma unroll
  for (int kc = 0; kc < 8; ++kc) {
    const float* hp = &hs[ln][kc * 16 + lh * 8];
    float4 u = *(const float4*)hp;
    float4 v = *(const float4*)(hp + 4);
    bf16x8 a;
    a[0] = (short)f2b(u.x * sc); a[1] = (short)f2b(u.y * sc);
    a[2] = (short)f2b(u.z * sc); a[3] = (short)f2b(u.w * sc);
    a[4] = (short)f2b(v.x * sc); a[5] = (short)f2b(v.y * sc);
    a[6] = (short)f2b(v.z * sc); a[7] = (short)f2b(v.w * sc);
    bfA[kc] = a;
    bfS[kc] = *(const bf16x8*)(fselfb + (size_t)row * DD + kc * 16 + lh * 8);
    bfB[kc] = *(const bf16x8*)(fbaseb + (size_t)row * DD + kc * 16 + lh * 8);
  }

  f32x16 acc;
#pragma unroll
  for (int r = 0; r < 16; ++r) acc[r] = 0.f;
#pragma unroll
  for (int kc = 0; kc < 8; ++kc)
    acc = __builtin_amdgcn_mfma_f32_32x32x16_bf16(
        wfrag(WL, cq * 32 + ln, kc, lh), bfB[kc], acc, 0, 0, 0);
  float sab = 0.f;
#pragma unroll
  for (int r = 0; r < 16; ++r) sab += fabsf(acc[r]);
  sab += __shfl_xor(sab, 32);
  if (l < 32) rowpart[w][ln] = sab;
  __syncthreads();
  const float rsum =
      rowpart[0][ln] + rowpart[1][ln] + rowpart[2][ln] + rowpart[3][ln];
  const float rinv = 1.f / fmaxf(rsum, EPSN);
  float basen[16];
#pragma unroll
  for (int r = 0; r < 16; ++r) basen[r] = acc[r] * rinv;

  stageW(Wmb, WL, t);
  __syncthreads();
#pragma unroll
  for (int r = 0; r < 16; ++r) acc[r] = 0.f;
#pragma unroll
  for (int kc = 0; kc < 8; ++kc)
    acc = __builtin_amdgcn_mfma_f32_32x32x16_bf16(
        wfrag(WL, cq * 32 + ln, kc, lh), bfA[kc], acc, 0, 0, 0);
#pragma unroll
  for (int r = 0; r < 16; ++r) {
    int c = cq * 32 + (r & 3) + 8 * (r >> 2) + 4 * lh;
    Mb[ln][(((c >> 3) ^ (ln & 15)) << 3) + (c & 7)] = f2b(acc[r] + blds[0][c]);
  }
  __syncthreads();

  stageW(Wsb, WL, t);
  __syncthreads();
#pragma unroll
  for (int r = 0; r < 16; ++r) acc[r] = 0.f;
#pragma unroll
  for (int kc = 0; kc < 8; ++kc)
    acc = __builtin_amdgcn_mfma_f32_32x32x16_bf16(
        wfrag(WL, cq * 32 + ln, kc, lh), bfS[kc], acc, 0, 0, 0);
#pragma unroll
  for (int r = 0; r < 16; ++r) {
    int c = cq * 32 + (r & 3) + 8 * (r >> 2) + 4 * lh;
    Sb[ln][(((c >> 3) ^ (ln & 15)) << 3) + (c & 7)] = f2b(acc[r] + blds[1][c]);
  }
  __syncthreads();

  stageW(Wg1b, WL, t);
  __syncthreads();
#pragma unroll
  for (int r = 0; r < 16; ++r) acc[r] = 0.f;
#pragma unroll
  for (int kc = 0; kc < 8; ++kc)
    acc = __builtin_amdgcn_mfma_f32_32x32x16_bf16(
        wfrag(WL, cq * 32 + ln, kc, lh), wfrag(Mb, ln, kc, lh), acc, 0, 0, 0);
  __syncthreads();
  stageW(Wg2b, WL, t);
  __syncthreads();
#pragma unroll
  for (int kc = 0; kc < 8; ++kc)
    acc = __builtin_amdgcn_mfma_f32_32x32x16_bf16(
        wfrag(WL, cq * 32 + ln, kc, lh), wfrag(Sb, ln, kc, lh), acc, 0, 0, 0);

  float val[16];
#pragma unroll
  for (int r = 0; r < 16; ++r) {
    int c = cq * 32 + (r & 3) + 8 * (r >> 2) + 4 * lh;
    float z = acc[r] + blds[2][c];
    float g = 1.f / (1.f + __expf(-z));
    int off = (((c >> 3) ^ (ln & 15)) << 3) + (c & 7);
    float mv = b2f(Mb[ln][off]);
    float sv = b2f(Sb[ln][off]);
    val[r] = basen[r] + g * mv + (1.f - g) * sv;
  }

  const int orow = t >> 3, c0 = (t & 7) * 4;
  if (outNorm) {
    __syncthreads();
#pragma unroll
    for (int r = 0; r < 16; ++r)
      tr[ln][cq * 32 + (r & 3) + 8 * (r >> 2) + 4 * lh] = basen[r];
    __syncthreads();
#pragma unroll
    for (int q = 0; q < 4; ++q)
      *(float4*)&outNorm[(size_t)(i0 + orow) * DD + c0 + 32 * q] =
          *(const float4*)&tr[orow][c0 + 32 * q];
  }
  __syncthreads();
#pragma unroll
  for (int r = 0; r < 16; ++r)
    tr[ln][cq * 32 + (r & 3) + 8 * (r >> 2) + 4 * lh] = val[r];
  __syncthreads();
  if (outValF) {
#pragma unroll
    for (int q = 0; q < 4; ++q)
      *(float4*)&outValF[(size_t)(i0 + orow) * DD + c0 + 32 * q] =
          *(const float4*)&tr[orow][c0 + 32 * q];
  }
  if (outValB) {
#pragma unroll
    for (int q = 0; q < 4; ++q) {
      float4 v = *(const float4*)&tr[orow][c0 + 32 * q];
      ushort4 o;
      o.x = f2b(v.x); o.y = f2b(v.y); o.z = f2b(v.z); o.w = f2b(v.w);
      *(ushort4*)&outValB[(size_t)(i0 + orow) * DD + c0 + 32 * q] = o;
    }
  }
}

// ---------------------------------------------------------------------------
extern "C" void kernel_launch(void* const* d_in, const int* in_sizes, int n_in,
                              void* d_out, int out_size, void* d_ws,
                              size_t ws_size, hipStream_t stream) {
  const float* f1 = (const float*)d_in[0];
  const float* f2 = (const float*)d_in[1];
  const float* Wd1 = (const float*)d_in[2];
  const float* bd1 = (const float*)d_in[3];
  const float* Wd2 = (const float*)d_in[4];
  const float* bd2 = (const float*)d_in[5];
  const float* Ws1 = (const float*)d_in[6];
  const float* bs1 = (const float*)d_in[7];
  const float* Ws2 = (const float*)d_in[8];
  const float* bs2 = (const float*)d_in[9];
  const float* g1W1 = (const float*)d_in[10];
  const float* g1b1 = (const float*)d_in[11];
  const float* g1W2 = (const float*)d_in[12];
  const float* g1b2 = (const float*)d_in[13];
  const float* g2W1 = (const float*)d_in[14];
  const float* g2b1 = (const float*)d_in[15];
  const float* g2W2 = (const float*)d_in[16];
  const float* g2b2 = (const float*)d_in[17];

  const int N = in_sizes[0] / DD;  // 8192
  const size_t ND = (size_t)N * DD;

  float* ws = (float*)d_ws;
  float* T1 = ws;                        // 16384 f
  float* T2 = T1 + DD * DD;              // 16384 f
  float* rb = T2 + DD * DD;              // N f
  unsigned short* f1bb = (unsigned short*)(rb + N);
  unsigned short* f2bb = f1bb + ND;
  unsigned short* f1nb = f2bb + ND;
  unsigned short* T1b = f1nb + ND;
  unsigned short* T2b = T1b + DD * DD;
  unsigned short* Wb0 = T2b + DD * DD;
  unsigned short* Wb1 = Wb0 + DD * DD;
  unsigned short* Wb2 = Wb1 + DD * DD;
  unsigned short* Wb3 = Wb2 + DD * DD;
  unsigned short* Wb4 = Wb3 + DD * DD;
  unsigned short* Wb5 = Wb4 + DD * DD;
  unsigned short* Wb6 = Wb5 + DD * DD;
  unsigned short* Wb7 = Wb6 + DD * DD;
  unsigned short* Hps = Wb7 + DD * DD;   // 6*ND ushort (12MB)
  float* out0 = (float*)d_out;
  float* out1 = out0 + ND;

  k_cvt2<<<dim3((int)(ND / 4 / 256), 2), 256, 0, stream>>>(f1, f2, f1bb, f2bb,
                                                           (int)(ND / 4));

  hipMemsetAsync(T1, 0, sizeof(float) * 2 * DD * DD, stream);
  k_ata<<<dim3(2, 2, 64), 256, 0, stream>>>(f1, T1, N / 64);
  k_ata<<<dim3(2, 2, 64), 256, 0, stream>>>(f2, T2, N / 64);
  k_cvt10<<<dim3(16, 10), 256, 0, stream>>>(Wd1, Ws1, g1W1, g1W2, Wd2, Ws2,
                                            g2W1, g2W2, T1, T2, Wb0, Wb1, Wb2,
                                            Wb3, Wb4, Wb5, Wb6, Wb7, T1b, T2b);

  // --- message block 1: d2 -> d1 ---
  hipMemsetAsync(rb, 0, sizeof(float) * N, stream);
  k_attn<<<dim3(N / 128, JSPLIT), 512, 0, stream>>>(
      f1bb, f2bb, Hps, (unsigned short*)out0, rb, N);
  k_post<<<N / 32, 256, 0, stream>>>(Hps, (unsigned short*)out0, rb, f2bb, f1bb,
                                     T1b, Wb0, bd1, Wb1, bs1, Wb2, g1b1, Wb3,
                                     g1b2, out0, nullptr, f1nb, N);

  // --- message block 2: d1 -> d2 ---
  hipMemsetAsync(rb, 0, sizeof(float) * N, stream);
  k_attn<<<dim3(N / 128, JSPLIT), 512, 0, stream>>>(
      f2bb, f1nb, Hps, (unsigned short*)out1, rb, N);
  k_post<<<N / 32, 256, 0, stream>>>(Hps, (unsigned short*)out1, rb, f1nb, f2bb,
                                     T2b, Wb4, bd2, Wb5, bs2, Wb6, g2b1, Wb7,
                                     g2b2, nullptr, out1, nullptr, N);
}